// Round 1
// baseline (3840.894 us; speedup 1.0000x reference)
//
#include <hip/hip_runtime.h>
#include <math.h>

// ---------------- problem constants ----------------
// B=8, CIN=64, H=W=128, N=16384, IC=128, P=110 (padded to 112), FN=3
// d_in order (setup_inputs dict order):
//  0 input_g  1 input_c
//  2 fg_0  3 fc_0  4 k1_w_0 5 v1_w_0 6 k2_w_0 7 v2_w_0
//  8 fg_1  9 fc_1 10 k1_w_1 11 v1_w_1 12 k2_w_1 13 v2_w_1
// 14 fg_2 15 fc_2 16 k1_w_2 17 v1_w_2 18 k2_w_2 19 v2_w_2
// 20 q1_w 21 q2_w 22 mask1_w 23 mask2_w 24 fuse1_w 25 fuse2_w
// 26 t_w 27 p_w 28 g_w 29 z_w 30 gn_w 31 gn_b

constexpr int    BB      = 8;
constexpr int    NN      = 16384;
constexpr size_t SZ_XQ_ST = (size_t)BB * 128 * NN;      // 16,777,216 floats
constexpr size_t SZ_XF_ST = (size_t)BB * 64 * NN;       //  8,388,608 floats

constexpr size_t OFF_XQ   = 0;                          // xq1,xq2 ; later reused for t,p,g fields
constexpr size_t OFF_XF   = 2 * SZ_XQ_ST;               // x_gray, x_color
constexpr size_t OFF_POOL = OFF_XF + 2 * SZ_XF_ST;      // pooled features, 788,480 floats
constexpr size_t OFF_XK   = OFF_POOL + 788480;          // [2][3][8][128][112]
constexpr size_t OFF_XV   = OFF_XK + 688128;
constexpr size_t OFF_MT   = OFF_XV + 688128;            // [2][3][8][112][64]
constexpr size_t OFF_W    = OFF_MT + 344064;            // [2][3][64][192]
constexpr size_t OFF_AT   = OFF_W + 73728;              // [2][64][64] (c-major)
constexpr size_t OFF_WT   = OFF_AT + 8192;              // t_wT,p_wT,g_wT [3][64][64]
constexpr size_t OFF_ATTC = OFF_WT + 12288;             // [8][8][3]
constexpr size_t OFF_MV   = OFF_ATTC + 192;             // [8][8][2]
// total = 52,934,976 floats = 211.7 MiB  (assumes ws_size >= this)

// alpha_k^2 constants: (2g)^k/k! * exp(-2g), g=1e-4
#define A0SQ 0.9998000199986667f
#define A1SQ 1.9996000399973335e-4f
#define A2SQ 1.9996000399973334e-8f

// ---------------- conv 3x3 SAME, 64->128 ch ----------------
__global__ __launch_bounds__(512) void k_conv3(const float* __restrict__ in,
                                               const float* __restrict__ w,
                                               float* __restrict__ out) {
    extern __shared__ float sIn[];                     // [64][3][130] = 99,840 B
    const int tid = threadIdx.x;
    const int y = blockIdx.x;
    const int b = blockIdx.y;
    const float* inb = in + (size_t)b * 64 * NN;
    for (int f = tid; f < 64 * 390; f += 512) {
        int ic = f / 390; int r = f - ic * 390; int dy = r / 130; int xx = r - dy * 130;
        int row = y + dy - 1; int col = xx - 1;
        float v = 0.f;
        if (row >= 0 && row < 128 && col >= 0 && col < 128)
            v = inb[((size_t)ic << 14) + (row << 7) + col];
        sIn[f] = v;
    }
    __syncthreads();
    const int px = tid & 127;
    const int ocg = __builtin_amdgcn_readfirstlane(tid >> 7);
    float acc[32];
#pragma unroll
    for (int j = 0; j < 32; ++j) acc[j] = 0.f;
#pragma unroll 1
    for (int ic = 0; ic < 64; ++ic) {
        float v[9];
        const int base = ic * 390 + px;
#pragma unroll
        for (int t = 0; t < 9; ++t) { int dy = t / 3, dx = t - dy * 3; v[t] = sIn[base + dy * 130 + dx]; }
        const float* wp = w + ((size_t)(ocg * 32) * 64 + ic) * 9;
#pragma unroll
        for (int j = 0; j < 32; ++j) {
            const float* wj = wp + (size_t)j * 576;
#pragma unroll
            for (int t = 0; t < 9; ++t) acc[j] = fmaf(wj[t], v[t], acc[j]);
        }
    }
    float* ob = out + (size_t)b * 128 * NN + (y << 7) + px;
#pragma unroll
    for (int j = 0; j < 32; ++j) ob[(size_t)(ocg * 32 + j) << 14] = acc[j];
}

// ---------------- pyramid pooling via 2D prefix sums ----------------
struct PoolPtrs { const float* src[6]; };               // fc0,fc1,fc2,fg0,fg1,fg2

__global__ __launch_bounds__(256) void k_pool(PoolPtrs pp, float* __restrict__ ws) {
    extern __shared__ float P[];                       // up to 128*129 floats
    const int plane = blockIdx.x;
    const int tid = threadIdx.x;
    int tI, h; size_t toff; int base;
    if      (plane < 512)  { tI = 0; h = 128; toff = 0;      base = 0;    }
    else if (plane < 1536) { tI = 1; h = 64;  toff = 56320;  base = 512;  }
    else if (plane < 3584) { tI = 2; h = 32;  toff = 168960; base = 1536; }
    else if (plane < 4096) { tI = 3; h = 128; toff = 394240; base = 3584; }
    else if (plane < 5120) { tI = 4; h = 64;  toff = 450560; base = 4096; }
    else                   { tI = 5; h = 32;  toff = 563200; base = 5120; }
    const int local = plane - base;
    const float* img = pp.src[tI] + (size_t)local * h * h;
    const int stride = h + 1;
    const int hh = h * h;
    for (int f = tid; f < hh; f += 256) {
        int r = f / h; int cc = f - r * h;
        P[r * stride + cc] = img[f];
    }
    __syncthreads();
    if (tid < h) {                                     // row prefix (register carry)
        float cur = 0.f; const int rb = tid * stride;
        for (int cc = 0; cc < h; ++cc) { cur += P[rb + cc]; P[rb + cc] = cur; }
    }
    __syncthreads();
    if (tid < h) {                                     // col prefix
        float cur = 0.f;
        for (int r = 0; r < h; ++r) { int a = r * stride + tid; cur += P[a]; P[a] = cur; }
    }
    __syncthreads();
    if (tid < 110) {
        int s, off2;
        if (tid == 0)      { s = 1; off2 = 0; }
        else if (tid < 10) { s = 3; off2 = 1; }
        else if (tid < 46) { s = 6; off2 = 10; }
        else               { s = 8; off2 = 46; }
        int r = tid - off2; int j = r / s; int q = r - j * s;
        const int n = h + 2;
        int ra = (j * n) / s,       rb2 = ((j + 1) * n + s - 1) / s;
        int ca = (q * n) / s,       cb2 = ((q + 1) * n + s - 1) / s;
        float area = (float)((rb2 - ra) * (cb2 - ca));
        int r0 = ra - 1; if (r0 < 0) r0 = 0;  int r1 = rb2 - 1; if (r1 > h) r1 = h;
        int c0 = ca - 1; if (c0 < 0) c0 = 0;  int c1 = cb2 - 1; if (c1 > h) c1 = h;
        float ssum = 0.f;
        if (r1 > r0 && c1 > c0) {
            int ri = r1 - 1, rj = r0 - 1, ci = c1 - 1, cj = c0 - 1;
            float f11 = P[ri * stride + ci];
            float f01 = (rj < 0) ? 0.f : P[rj * stride + ci];
            float f10 = (cj < 0) ? 0.f : P[ri * stride + cj];
            float f00 = (rj < 0 || cj < 0) ? 0.f : P[rj * stride + cj];
            ssum = f11 - f01 - f10 + f00;
        }
        ws[OFF_POOL + toff + (size_t)local * 110 + tid] = ssum / area;
    }
}

// ---------------- small weight precomputes ----------------
__global__ __launch_bounds__(256) void k_pkw(const float* __restrict__ f1, const float* __restrict__ f2,
                                             const float* __restrict__ m1, const float* __restrict__ m2,
                                             const float* __restrict__ tw, const float* __restrict__ pw,
                                             const float* __restrict__ gw, float* __restrict__ ws) {
    int id = blockIdx.x * 256 + threadIdx.x;
    if (id < 73728) {                                  // W[st][i][o][c] = sum_k fuse[o][64i+k]*mask[k][c]
        int c = id % 192; int t = id / 192; int o = t & 63; int t2 = t >> 6; int i = t2 % 3; int st = t2 / 3;
        const float* fu = st ? f2 : f1; const float* ma = st ? m2 : m1;
        float s = 0.f;
        for (int k = 0; k < 64; ++k) s = fmaf(fu[o * 192 + i * 64 + k], ma[k * 192 + c], s);
        ws[OFF_W + id] = s;
    } else if (id < 81920) {                           // AT[st][c][o] = sum_{i,k} fuse[o][64i+k]*mask[k][c]
        int x = id - 73728; int o = x & 63; int c = (x >> 6) & 63; int st = x >> 12;
        const float* fu = st ? f2 : f1; const float* ma = st ? m2 : m1;
        float s = 0.f;
        for (int k = 0; k < 192; ++k) s = fmaf(fu[o * 192 + k], ma[(k & 63) * 192 + c], s);
        ws[OFF_AT + (size_t)st * 4096 + c * 64 + o] = s;
    } else if (id < 94208) {                           // WT[f][c][o] = w[o][c]
        int x = id - 81920; int o = x & 63; int c = (x >> 6) & 63; int f = x >> 12;
        const float* src = (f == 0) ? tw : ((f == 1) ? pw : gw);
        ws[OFF_WT + (size_t)f * 4096 + c * 64 + o] = src[o * 64 + c];
    }
}

// ---------------- xk / xv from pooled features ----------------
struct KvPtrs { const float* k1[3]; const float* k2[3]; const float* v1[3]; const float* v2[3]; };

__global__ __launch_bounds__(256) void k_xkxv(KvPtrs kp, float* __restrict__ ws) {
    int id = blockIdx.x * 256 + threadIdx.x;           // 2*688,128 total
    int isV = 0;
    if (id >= 688128) { isV = 1; id -= 688128; }
    int p = id % 112; int t1 = id / 112; int C = t1 & 127; int t2 = t1 >> 7;
    int b = t2 & 7; int t3 = t2 >> 3; int i = t3 % 3; int st = t3 / 3;
    const int ci = 64 << i;
    size_t poff = (size_t)st * 394240 + (i >= 1 ? 56320 : 0) + (i >= 2 ? 112640 : 0);
    const float* kw = isV ? (st ? kp.v2[i] : kp.v1[i]) : (st ? kp.k2[i] : kp.k1[i]);
    float s = 0.f;
    if (p < 110) {
        const float* pl = ws + OFF_POOL + poff + (size_t)b * ci * 110 + p;
        for (int ic = 0; ic < ci; ++ic) s = fmaf(kw[C * ci + ic], pl[(size_t)ic * 110], s);
    }
    ws[(isV ? OFF_XV : OFF_XK) + id] = s;
}

// ---------------- M_T[p][o] = sum_r W[o][64+r] * xv[r][p] ----------------
__global__ __launch_bounds__(256) void k_mt(float* __restrict__ ws) {
    int id = blockIdx.x * 256 + threadIdx.x;           // 344,064
    int o = id & 63; int t1 = id >> 6; int p = t1 % 112; int t2 = t1 / 112;  // t2=(st*3+i)*8+b
    int sti = t2 >> 3;
    const float* Wrow = ws + OFF_W + ((size_t)sti * 64 + o) * 192 + 64;
    const float* xv = ws + OFF_XV + (size_t)t2 * 128 * 112 + p;
    float s = 0.f;
    for (int r = 0; r < 128; ++r) s = fmaf(Wrow[r], xv[(size_t)r * 112], s);
    ws[OFF_MT + id] = s;
}

// ---------------- fused attention: S -> softmax -> M@P -> +A@in -> tanh -> +in ----------------
__global__ __launch_bounds__(128) void k_attn(float* __restrict__ ws,
                                              const float* __restrict__ g_in,
                                              const float* __restrict__ c_in) {
    __shared__ float P[64 * 113];
    const int tid = threadIdx.x;
    const int col = tid & 63;
    const int half = __builtin_amdgcn_readfirstlane(tid >> 6);
    const int n0 = blockIdx.x << 6;
    const int b = blockIdx.y;
    const int st = blockIdx.z;
    const float* xq = ws + OFF_XQ + (size_t)st * SZ_XQ_ST + (size_t)b * 128 * NN + n0 + col;
    const int hb = half * 56;
    const int ob = half * 32;
    float acc[32];
#pragma unroll
    for (int j = 0; j < 32; ++j) acc[j] = 0.f;
#pragma unroll 1
    for (int i = 0; i < 3; ++i) {
        float S[56];
#pragma unroll
        for (int j = 0; j < 56; ++j) S[j] = 0.f;
        const float* xk = ws + OFF_XK + (size_t)((st * 3 + i) * 8 + b) * 128 * 112 + hb;
#pragma unroll 1
        for (int c = 0; c < 128; ++c) {
            float qv = xq[(size_t)c << 14];
            const float* xr = xk + (size_t)c * 112;
#pragma unroll
            for (int j = 0; j < 56; ++j) S[j] = fmaf(xr[j], qv, S[j]);
        }
#pragma unroll
        for (int j = 0; j < 56; ++j) {
            float v = fminf(fmaxf(S[j], -64.f), 64.f);
            P[col * 113 + hb + j] = v;
        }
        if (half == 1) { P[col * 113 + 110] = -64.f; P[col * 113 + 111] = -64.f; }
        __syncthreads();
        if (half == 0) {
            float m = -1e30f;
            for (int p = 0; p < 112; ++p) m = fmaxf(m, P[col * 113 + p]);
            float ssum = 0.f;
            for (int p = 0; p < 112; ++p) { float e = __expf(P[col * 113 + p] - m); P[col * 113 + p] = e; ssum += e; }
            float inv = 1.f / ssum;
            for (int p = 0; p < 112; ++p) P[col * 113 + p] *= inv;
        }
        __syncthreads();
        const float* MTp = ws + OFF_MT + (size_t)((st * 3 + i) * 8 + b) * 112 * 64 + ob;
#pragma unroll 1
        for (int k = 0; k < 112; ++k) {
            float pv = P[col * 113 + k];
            const float* mr = MTp + (size_t)k * 64;
#pragma unroll
            for (int j = 0; j < 32; ++j) acc[j] = fmaf(mr[j], pv, acc[j]);
        }
        __syncthreads();
    }
    const float* gin = (st ? c_in : g_in) + (size_t)b * 64 * NN + n0 + col;
    const float* AT = ws + OFF_AT + (size_t)st * 4096 + ob;
#pragma unroll 1
    for (int c = 0; c < 64; ++c) {
        float gv = gin[(size_t)c << 14];
        const float* ar = AT + (size_t)c * 64;
#pragma unroll
        for (int j = 0; j < 32; ++j) acc[j] = fmaf(ar[j], gv, acc[j]);
    }
    float* xf = ws + OFF_XF + (size_t)st * SZ_XF_ST + (size_t)b * 64 * NN + n0 + col;
#pragma unroll
    for (int j = 0; j < 32; ++j) {
        size_t o = (size_t)(ob + j);
        xf[o << 14] = tanhf(acc[j]) + gin[o << 14];
    }
}

// ---------------- t,p,g fields: [64,64] @ [64,N] per batch ----------------
__global__ __launch_bounds__(256) void k_tpg(float* __restrict__ ws) {
    __shared__ float X[64 * 65];
    const int tid = threadIdx.x;
    const int n0 = blockIdx.x << 6; const int b = blockIdx.y; const int f = blockIdx.z;
    const float* src = ws + OFF_XF + (f == 0 ? 0 : SZ_XF_ST) + (size_t)b * 64 * NN;
    for (int ff = tid; ff < 4096; ff += 256) {
        int c = ff >> 6; int nn2 = ff & 63;
        X[c * 65 + nn2] = src[((size_t)c << 14) + n0 + nn2];
    }
    __syncthreads();
    const int col = tid & 63; const int qg = __builtin_amdgcn_readfirstlane(tid >> 6);
    const float* WT = ws + OFF_WT + (size_t)f * 4096 + qg * 16;
    float acc[16];
#pragma unroll
    for (int j = 0; j < 16; ++j) acc[j] = 0.f;
#pragma unroll 1
    for (int c = 0; c < 64; ++c) {
        float xv = X[c * 65 + col];
        const float* wr = WT + (size_t)c * 64;
#pragma unroll
        for (int j = 0; j < 16; ++j) acc[j] = fmaf(wr[j], xv, acc[j]);
    }
    float* dst = ws + OFF_XQ + (size_t)f * SZ_XF_ST + (size_t)b * 64 * NN + n0 + col;
#pragma unroll
    for (int j = 0; j < 16; ++j) dst[(size_t)(qg * 16 + j) << 14] = acc[j];
}

// ---------------- attention coefficients per (b,g) ----------------
__global__ __launch_bounds__(256) void k_attred(float* __restrict__ ws) {
    __shared__ float r0[256], r1[256], r2[256];
    const int g = blockIdx.x, b = blockIdx.y, tid = threadIdx.x;
    const float* pf = ws + OFF_XQ + SZ_XF_ST + ((size_t)(b * 64 + g * 8) << 14);
    const float* gf = pf + SZ_XF_ST;
    float s0 = 0.f, s1 = 0.f, s2 = 0.f;
    for (int idx = tid; idx < 131072; idx += 256) {
        float pv = pf[idx], gv = gf[idx];
        s0 += gv; s1 = fmaf(pv, gv, s1); s2 = fmaf(pv * pv, gv, s2);
    }
    r0[tid] = s0; r1[tid] = s1; r2[tid] = s2;
    __syncthreads();
    for (int w = 128; w > 0; w >>= 1) {
        if (tid < w) { r0[tid] += r0[tid + w]; r1[tid] += r1[tid + w]; r2[tid] += r2[tid + w]; }
        __syncthreads();
    }
    if (tid == 0) {
        float* a = ws + OFF_ATTC + (size_t)(b * 8 + g) * 3;
        a[0] = A0SQ * r0[0]; a[1] = A1SQ * r1[0]; a[2] = A2SQ * r2[0];
    }
}

// ---------------- GroupNorm stats of z(y(t)) per (b,g) ----------------
__global__ __launch_bounds__(256) void k_stats(float* __restrict__ ws, const float* __restrict__ zw) {
    __shared__ float r0[256], r1[256];
    const int g = blockIdx.x, b = blockIdx.y, tid = threadIdx.x;
    const float* tf = ws + OFF_XQ + ((size_t)(b * 64 + g * 8) << 14);
    const float* a = ws + OFF_ATTC + (size_t)(b * 8 + g) * 3;
    const float c0 = a[0], c1 = a[1], c2 = a[2];
    const float* z = zw + (size_t)g * 64;
    float sum = 0.f, ssq = 0.f;
    for (int n = tid; n < 16384; n += 256) {
        float y[8];
#pragma unroll
        for (int pl = 0; pl < 8; ++pl) { float tv = tf[((size_t)pl << 14) + n]; y[pl] = fmaf(fmaf(c2, tv, c1), tv, c0); }
#pragma unroll
        for (int o = 0; o < 8; ++o) {
            float xz = 0.f;
#pragma unroll
            for (int i2 = 0; i2 < 8; ++i2) xz = fmaf(z[o * 8 + i2], y[i2], xz);
            sum += xz; ssq = fmaf(xz, xz, ssq);
        }
    }
    r0[tid] = sum; r1[tid] = ssq;
    __syncthreads();
    for (int w = 128; w > 0; w >>= 1) {
        if (tid < w) { r0[tid] += r0[tid + w]; r1[tid] += r1[tid + w]; }
        __syncthreads();
    }
    if (tid == 0) {
        float mean = r0[0] * (1.f / 131072.f);
        float var = r1[0] * (1.f / 131072.f) - mean * mean;
        float* mv = ws + OFF_MV + (size_t)(b * 8 + g) * 2;
        mv[0] = mean; mv[1] = rsqrtf(var + 1e-5f);
    }
}

// ---------------- final: recompute y,xz ; GN affine ; + x_gray + input_g ----------------
__global__ __launch_bounds__(256) void k_final(float* __restrict__ ws, const float* __restrict__ zw,
                                               const float* __restrict__ gnw, const float* __restrict__ gnb,
                                               const float* __restrict__ g_in, float* __restrict__ out) {
    int id = blockIdx.x * 256 + threadIdx.x;           // < 1,048,576
    int n = id & 16383; int g = (id >> 14) & 7; int b = id >> 17;
    const float* a = ws + OFF_ATTC + (size_t)(b * 8 + g) * 3;
    const float c0 = a[0], c1 = a[1], c2 = a[2];
    const float* mv = ws + OFF_MV + (size_t)(b * 8 + g) * 2;
    const float mean = mv[0], istd = mv[1];
    const float* z = zw + (size_t)g * 64;
    const float* tf = ws + OFF_XQ + ((size_t)(b * 64 + g * 8) << 14) + n;
    float y[8];
#pragma unroll
    for (int pl = 0; pl < 8; ++pl) { float tv = tf[(size_t)pl << 14]; y[pl] = fmaf(fmaf(c2, tv, c1), tv, c0); }
    const size_t cb = ((size_t)(b * 64 + g * 8) << 14) + n;
    const float* xg = ws + OFF_XF + cb;
    const float* gi = g_in + cb;
    float* op = out + cb;
#pragma unroll
    for (int o = 0; o < 8; ++o) {
        float xz = 0.f;
#pragma unroll
        for (int i2 = 0; i2 < 8; ++i2) xz = fmaf(z[o * 8 + i2], y[i2], xz);
        int ch = g * 8 + o;
        float v = fmaf((xz - mean) * istd, gnw[ch], gnb[ch]) + xg[(size_t)o << 14] + gi[(size_t)o << 14];
        op[(size_t)o << 14] = v;
    }
}

// ---------------- host launch ----------------
extern "C" void kernel_launch(void* const* d_in, const int* in_sizes, int n_in,
                              void* d_out, int out_size, void* d_ws, size_t ws_size,
                              hipStream_t stream) {
    const float* in_g = (const float*)d_in[0];
    const float* in_c = (const float*)d_in[1];
    float* ws = (float*)d_ws;
    float* out = (float*)d_out;

    // conv q1/q2 -> xq regions
    k_conv3<<<dim3(128, 8), 512, 64 * 390 * 4, stream>>>(in_g, (const float*)d_in[20], ws + OFF_XQ);
    k_conv3<<<dim3(128, 8), 512, 64 * 390 * 4, stream>>>(in_c, (const float*)d_in[21], ws + OFF_XQ + SZ_XQ_ST);

    // pyramid pooling of raw features
    PoolPtrs pp;
    pp.src[0] = (const float*)d_in[3];  pp.src[1] = (const float*)d_in[9];  pp.src[2] = (const float*)d_in[15];
    pp.src[3] = (const float*)d_in[2];  pp.src[4] = (const float*)d_in[8];  pp.src[5] = (const float*)d_in[14];
    k_pool<<<7168, 256, 128 * 129 * 4, stream>>>(pp, ws);

    // weight precomputes
    k_pkw<<<368, 256, 0, stream>>>((const float*)d_in[24], (const float*)d_in[25],
                                   (const float*)d_in[22], (const float*)d_in[23],
                                   (const float*)d_in[26], (const float*)d_in[27],
                                   (const float*)d_in[28], ws);

    // xk, xv
    KvPtrs kp;
    kp.k1[0] = (const float*)d_in[4];  kp.k1[1] = (const float*)d_in[10]; kp.k1[2] = (const float*)d_in[16];
    kp.k2[0] = (const float*)d_in[6];  kp.k2[1] = (const float*)d_in[12]; kp.k2[2] = (const float*)d_in[18];
    kp.v1[0] = (const float*)d_in[5];  kp.v1[1] = (const float*)d_in[11]; kp.v1[2] = (const float*)d_in[17];
    kp.v2[0] = (const float*)d_in[7];  kp.v2[1] = (const float*)d_in[13]; kp.v2[2] = (const float*)d_in[19];
    k_xkxv<<<5376, 256, 0, stream>>>(kp, ws);

    // M_T
    k_mt<<<1344, 256, 0, stream>>>(ws);

    // fused attention -> x_gray / x_color
    k_attn<<<dim3(256, 8, 2), 128, 0, stream>>>(ws, in_g, in_c);

    // t,p,g fields (reuse xq region)
    k_tpg<<<dim3(256, 8, 3), 256, 0, stream>>>(ws);

    // attention coefficients, GN stats, final
    k_attred<<<dim3(8, 8), 256, 0, stream>>>(ws);
    k_stats<<<dim3(8, 8), 256, 0, stream>>>(ws, (const float*)d_in[29]);
    k_final<<<4096, 256, 0, stream>>>(ws, (const float*)d_in[29], (const float*)d_in[30],
                                      (const float*)d_in[31], in_g, out);
}

// Round 2
// 1703.567 us; speedup vs baseline: 2.2546x; 2.2546x over previous
//
#include <hip/hip_runtime.h>
#include <math.h>

// ---------------- problem constants ----------------
// B=8, CIN=64, H=W=128, N=16384, IC=128, P=110 (padded to 112), FN=3
constexpr int    BB      = 8;
constexpr int    NN      = 16384;
constexpr size_t SZ_XQ_ST = (size_t)BB * 128 * NN;      // 16,777,216 floats
constexpr size_t SZ_XF_ST = (size_t)BB * 64 * NN;       //  8,388,608 floats

constexpr size_t OFF_XQ   = 0;                          // xq1,xq2 ; later reused for t,p,g fields
constexpr size_t OFF_XF   = 2 * SZ_XQ_ST;               // x_gray, x_color (pre-attn: Xt/Wt staging)
constexpr size_t OFF_POOL = OFF_XF + 2 * SZ_XF_ST;      // pooled features, 788,480 floats
constexpr size_t OFF_XK   = OFF_POOL + 788480;          // [2][3][8][128][112]
constexpr size_t OFF_XV   = OFF_XK + 688128;
constexpr size_t OFF_MT   = OFF_XV + 688128;            // [2][3][8][112][64]
constexpr size_t OFF_W    = OFF_MT + 344064;            // [2][3][64][192]
constexpr size_t OFF_AT   = OFF_W + 73728;              // [2][64][64] (c-major)
constexpr size_t OFF_WT   = OFF_AT + 8192;              // t_wT,p_wT,g_wT [3][64][64]
constexpr size_t OFF_ATTC = OFF_WT + 12288;             // [8][8][3]
constexpr size_t OFF_MV   = OFF_ATTC + 192;             // [8][8][2]
// total = 52,934,976 floats = 211.7 MiB

// Transient staging inside the XF region (consumed before k_attn overwrites it):
//   Xt_g : bf16[8][128][128][64] at float-slot OFF_XF            (4,194,304 slots)
//   Xt_c : bf16 ...              at OFF_XF +  4,194,304
//   Wt_g : bf16[9][128][64]      at OFF_XF +  8,388,608          (36,864 slots)
//   Wt_c : bf16[9][128][64]      at OFF_XF +  8,425,472

#define A0SQ 0.9998000199986667f
#define A1SQ 1.9996000399973335e-4f
#define A2SQ 1.9996000399973334e-8f

typedef __attribute__((ext_vector_type(8))) short bf16x8;
typedef __attribute__((ext_vector_type(4))) float f32x4;

__device__ inline ushort f2bf(float f) {
    uint u = __float_as_uint(f);
    return (ushort)((u + 0x7fffu + ((u >> 16) & 1u)) >> 16);
}

// ---------------- input transpose: f32 [64][128][128] -> bf16 [y][x][64] ----------------
__global__ __launch_bounds__(256) void k_xt(const float* __restrict__ in, ushort* __restrict__ xt) {
    __shared__ float L[64 * 130];
    const int y = blockIdx.x, b = blockIdx.y, tid = threadIdx.x;
    const float* ib = in + (((size_t)b * 64) << 14) + (y << 7);
    for (int r = 0; r < 32; ++r) {
        int idx = tid + (r << 8); int ch = idx >> 7; int x = idx & 127;
        L[ch * 130 + x] = ib[((size_t)ch << 14) + x];
    }
    __syncthreads();
    const int x = tid >> 1, seg = tid & 1;
    ushort* ob = xt + ((size_t)(b * 128 + y) * 128 + x) * 64 + seg * 32;
    uint pk[16];
#pragma unroll
    for (int c = 0; c < 16; ++c) {
        uint lo = f2bf(L[(seg * 32 + 2 * c) * 130 + x]);
        uint hi = f2bf(L[(seg * 32 + 2 * c + 1) * 130 + x]);
        pk[c] = lo | (hi << 16);
    }
    uint4* o4 = (uint4*)ob;
#pragma unroll
    for (int c = 0; c < 4; ++c) o4[c] = make_uint4(pk[4 * c], pk[4 * c + 1], pk[4 * c + 2], pk[4 * c + 3]);
}

// ---------------- weight re-layout: f32 [oc][ic][3][3] -> bf16 [t][oc][ic] ----------------
__global__ __launch_bounds__(256) void k_wt(const float* __restrict__ w1, const float* __restrict__ w2,
                                            ushort* __restrict__ wt1, ushort* __restrict__ wt2) {
    int id = blockIdx.x * 256 + threadIdx.x;            // 147,456
    if (id >= 147456) return;
    int cs = id / 73728; int rem = id - cs * 73728;
    int t = rem >> 13; int oc = (rem >> 6) & 127; int ic = rem & 63;
    const float* w = cs ? w2 : w1;
    (cs ? wt2 : wt1)[rem] = f2bf(w[((size_t)(oc * 64 + ic)) * 9 + t]);
}

// ---------------- conv 3x3 SAME 64->128 as bf16 MFMA implicit GEMM ----------------
// block: 128 oc x 128 px (one row y); 9 K-steps (taps) of K=64 ic
__global__ __launch_bounds__(256) void k_convm(const ushort* __restrict__ Xt, const ushort* __restrict__ Wt,
                                               float* __restrict__ out) {
    __shared__ ushort lds_w[128 * 72];                  // [oc][ic], pitch 72
    __shared__ ushort lds_x[128 * 72];                  // [x][ic],  pitch 72
    const int tid = threadIdx.x;
    const int y = blockIdx.x, b = blockIdx.y;
    const int l = tid & 63;
    const int wv = tid >> 6;                            // wave 0..3 -> oc0 = wv*32
    const int lr = l & 15;
    const int q = l >> 4;
    const int cr = tid >> 1;                            // staging row 0..127
    const int seg = tid & 1;                            // 32-ic half

    f32x4 acc[2][8];
#pragma unroll
    for (int f = 0; f < 2; ++f)
#pragma unroll
        for (int g = 0; g < 8; ++g)
#pragma unroll
            for (int r = 0; r < 4; ++r) acc[f][g][r] = 0.f;

#pragma unroll 1
    for (int t = 0; t < 9; ++t) {
        const int dy = t / 3, dx = t - dy * 3;
        const int srow = y + dy - 1;
        // stage W tile
        {
            const uint4* s = (const uint4*)(Wt + ((size_t)(t * 128 + cr) * 64 + seg * 32));
            uint4* d = (uint4*)(lds_w + cr * 72 + seg * 32);
            d[0] = s[0]; d[1] = s[1]; d[2] = s[2]; d[3] = s[3];
        }
        // stage X tile (zero at borders)
        {
            const int sx = cr + dx - 1;
            const bool v = (srow >= 0) & (srow < 128) & (sx >= 0) & (sx < 128);
            const uint4* s = (const uint4*)(Xt + (((size_t)(b * 128 + srow) * 128 + sx) * 64 + seg * 32));
            uint4 z = make_uint4(0, 0, 0, 0);
            uint4 r0 = v ? s[0] : z, r1 = v ? s[1] : z, r2 = v ? s[2] : z, r3 = v ? s[3] : z;
            uint4* d = (uint4*)(lds_x + cr * 72 + seg * 32);
            d[0] = r0; d[1] = r1; d[2] = r2; d[3] = r3;
        }
        __syncthreads();
#pragma unroll
        for (int h = 0; h < 2; ++h) {
            const int ko = h * 32 + q * 8;
            bf16x8 a0 = *(const bf16x8*)(lds_w + (wv * 32 + lr) * 72 + ko);
            bf16x8 a1 = *(const bf16x8*)(lds_w + (wv * 32 + 16 + lr) * 72 + ko);
#pragma unroll
            for (int g = 0; g < 8; ++g) {
                bf16x8 bb = *(const bf16x8*)(lds_x + (g * 16 + lr) * 72 + ko);
                acc[0][g] = __builtin_amdgcn_mfma_f32_16x16x32_bf16(a0, bb, acc[0][g], 0, 0, 0);
                acc[1][g] = __builtin_amdgcn_mfma_f32_16x16x32_bf16(a1, bb, acc[1][g], 0, 0, 0);
            }
        }
        __syncthreads();
    }
    float* ob = out + ((size_t)b * 128 << 14) + (y << 7);
#pragma unroll
    for (int f = 0; f < 2; ++f)
#pragma unroll
        for (int g = 0; g < 8; ++g)
#pragma unroll
            for (int r = 0; r < 4; ++r) {
                int oc = wv * 32 + f * 16 + q * 4 + r;
                int x = g * 16 + lr;
                ob[((size_t)oc << 14) + x] = acc[f][g][r];
            }
}

// ---------------- pyramid pooling via 2D prefix sums ----------------
struct PoolPtrs { const float* src[6]; };               // fc0,fc1,fc2,fg0,fg1,fg2

__global__ __launch_bounds__(256) void k_pool(PoolPtrs pp, float* __restrict__ ws) {
    extern __shared__ float P[];
    const int plane = blockIdx.x;
    const int tid = threadIdx.x;
    int tI, h; size_t toff; int base;
    if      (plane < 512)  { tI = 0; h = 128; toff = 0;      base = 0;    }
    else if (plane < 1536) { tI = 1; h = 64;  toff = 56320;  base = 512;  }
    else if (plane < 3584) { tI = 2; h = 32;  toff = 168960; base = 1536; }
    else if (plane < 4096) { tI = 3; h = 128; toff = 394240; base = 3584; }
    else if (plane < 5120) { tI = 4; h = 64;  toff = 450560; base = 4096; }
    else                   { tI = 5; h = 32;  toff = 563200; base = 5120; }
    const int local = plane - base;
    const float* img = pp.src[tI] + (size_t)local * h * h;
    const int stride = h + 1;
    const int hh = h * h;
    for (int f = tid; f < hh; f += 256) {
        int r = f / h; int cc = f - r * h;
        P[r * stride + cc] = img[f];
    }
    __syncthreads();
    if (tid < h) {
        float cur = 0.f; const int rb = tid * stride;
        for (int cc = 0; cc < h; ++cc) { cur += P[rb + cc]; P[rb + cc] = cur; }
    }
    __syncthreads();
    if (tid < h) {
        float cur = 0.f;
        for (int r = 0; r < h; ++r) { int a = r * stride + tid; cur += P[a]; P[a] = cur; }
    }
    __syncthreads();
    if (tid < 110) {
        int s, off2;
        if (tid == 0)      { s = 1; off2 = 0; }
        else if (tid < 10) { s = 3; off2 = 1; }
        else if (tid < 46) { s = 6; off2 = 10; }
        else               { s = 8; off2 = 46; }
        int r = tid - off2; int j = r / s; int q = r - j * s;
        const int n = h + 2;
        int ra = (j * n) / s,       rb2 = ((j + 1) * n + s - 1) / s;
        int ca = (q * n) / s,       cb2 = ((q + 1) * n + s - 1) / s;
        float area = (float)((rb2 - ra) * (cb2 - ca));
        int r0 = ra - 1; if (r0 < 0) r0 = 0;  int r1 = rb2 - 1; if (r1 > h) r1 = h;
        int c0 = ca - 1; if (c0 < 0) c0 = 0;  int c1 = cb2 - 1; if (c1 > h) c1 = h;
        float ssum = 0.f;
        if (r1 > r0 && c1 > c0) {
            int ri = r1 - 1, rj = r0 - 1, ci = c1 - 1, cj = c0 - 1;
            float f11 = P[ri * stride + ci];
            float f01 = (rj < 0) ? 0.f : P[rj * stride + ci];
            float f10 = (cj < 0) ? 0.f : P[ri * stride + cj];
            float f00 = (rj < 0 || cj < 0) ? 0.f : P[rj * stride + cj];
            ssum = f11 - f01 - f10 + f00;
        }
        ws[OFF_POOL + toff + (size_t)local * 110 + tid] = ssum / area;
    }
}

// ---------------- small weight precomputes ----------------
__global__ __launch_bounds__(256) void k_pkw(const float* __restrict__ f1, const float* __restrict__ f2,
                                             const float* __restrict__ m1, const float* __restrict__ m2,
                                             const float* __restrict__ tw, const float* __restrict__ pw,
                                             const float* __restrict__ gw, float* __restrict__ ws) {
    int id = blockIdx.x * 256 + threadIdx.x;
    if (id < 73728) {
        int c = id % 192; int t = id / 192; int o = t & 63; int t2 = t >> 6; int i = t2 % 3; int st = t2 / 3;
        const float* fu = st ? f2 : f1; const float* ma = st ? m2 : m1;
        float s = 0.f;
        for (int k = 0; k < 64; ++k) s = fmaf(fu[o * 192 + i * 64 + k], ma[k * 192 + c], s);
        ws[OFF_W + id] = s;
    } else if (id < 81920) {
        int x = id - 73728; int o = x & 63; int c = (x >> 6) & 63; int st = x >> 12;
        const float* fu = st ? f2 : f1; const float* ma = st ? m2 : m1;
        float s = 0.f;
        for (int k = 0; k < 192; ++k) s = fmaf(fu[o * 192 + k], ma[(k & 63) * 192 + c], s);
        ws[OFF_AT + (size_t)st * 4096 + c * 64 + o] = s;
    } else if (id < 94208) {
        int x = id - 81920; int o = x & 63; int c = (x >> 6) & 63; int f = x >> 12;
        const float* src = (f == 0) ? tw : ((f == 1) ? pw : gw);
        ws[OFF_WT + (size_t)f * 4096 + c * 64 + o] = src[o * 64 + c];
    }
}

// ---------------- xk / xv from pooled features ----------------
struct KvPtrs { const float* k1[3]; const float* k2[3]; const float* v1[3]; const float* v2[3]; };

__global__ __launch_bounds__(256) void k_xkxv(KvPtrs kp, float* __restrict__ ws) {
    int id = blockIdx.x * 256 + threadIdx.x;
    int isV = 0;
    if (id >= 688128) { isV = 1; id -= 688128; }
    int p = id % 112; int t1 = id / 112; int C = t1 & 127; int t2 = t1 >> 7;
    int b = t2 & 7; int t3 = t2 >> 3; int i = t3 % 3; int st = t3 / 3;
    const int ci = 64 << i;
    size_t poff = (size_t)st * 394240 + (i >= 1 ? 56320 : 0) + (i >= 2 ? 112640 : 0);
    const float* kw = isV ? (st ? kp.v2[i] : kp.v1[i]) : (st ? kp.k2[i] : kp.k1[i]);
    float s = 0.f;
    if (p < 110) {
        const float* pl = ws + OFF_POOL + poff + (size_t)b * ci * 110 + p;
        for (int ic = 0; ic < ci; ++ic) s = fmaf(kw[C * ci + ic], pl[(size_t)ic * 110], s);
    }
    ws[(isV ? OFF_XV : OFF_XK) + id] = s;
}

// ---------------- M_T[p][o] = sum_r W[o][64+r] * xv[r][p] ----------------
__global__ __launch_bounds__(256) void k_mt(float* __restrict__ ws) {
    int id = blockIdx.x * 256 + threadIdx.x;
    int o = id & 63; int t1 = id >> 6; int p = t1 % 112; int t2 = t1 / 112;
    int sti = t2 >> 3;
    const float* Wrow = ws + OFF_W + ((size_t)sti * 64 + o) * 192 + 64;
    const float* xv = ws + OFF_XV + (size_t)t2 * 128 * 112 + p;
    float s = 0.f;
    for (int r = 0; r < 128; ++r) s = fmaf(Wrow[r], xv[(size_t)r * 112], s);
    ws[OFF_MT + id] = s;
}

// ---------------- fused attention ----------------
__global__ __launch_bounds__(128) void k_attn(float* __restrict__ ws,
                                              const float* __restrict__ g_in,
                                              const float* __restrict__ c_in) {
    __shared__ float P[64 * 113];
    const int tid = threadIdx.x;
    const int col = tid & 63;
    const int half = __builtin_amdgcn_readfirstlane(tid >> 6);
    const int n0 = blockIdx.x << 6;
    const int b = blockIdx.y;
    const int st = blockIdx.z;
    const float* xq = ws + OFF_XQ + (size_t)st * SZ_XQ_ST + (size_t)b * 128 * NN + n0 + col;
    const int hb = half * 56;
    const int ob = half * 32;
    float acc[32];
#pragma unroll
    for (int j = 0; j < 32; ++j) acc[j] = 0.f;
#pragma unroll 1
    for (int i = 0; i < 3; ++i) {
        float S[56];
#pragma unroll
        for (int j = 0; j < 56; ++j) S[j] = 0.f;
        const float* xk = ws + OFF_XK + (size_t)((st * 3 + i) * 8 + b) * 128 * 112 + hb;
#pragma unroll 1
        for (int c = 0; c < 128; ++c) {
            float qv = xq[(size_t)c << 14];
            const float* xr = xk + (size_t)c * 112;
#pragma unroll
            for (int j = 0; j < 56; ++j) S[j] = fmaf(xr[j], qv, S[j]);
        }
#pragma unroll
        for (int j = 0; j < 56; ++j) {
            float v = fminf(fmaxf(S[j], -64.f), 64.f);
            P[col * 113 + hb + j] = v;
        }
        if (half == 1) { P[col * 113 + 110] = -64.f; P[col * 113 + 111] = -64.f; }
        __syncthreads();
        if (half == 0) {
            float m = -1e30f;
            for (int p = 0; p < 112; ++p) m = fmaxf(m, P[col * 113 + p]);
            float ssum = 0.f;
            for (int p = 0; p < 112; ++p) { float e = __expf(P[col * 113 + p] - m); P[col * 113 + p] = e; ssum += e; }
            float inv = 1.f / ssum;
            for (int p = 0; p < 112; ++p) P[col * 113 + p] *= inv;
        }
        __syncthreads();
        const float* MTp = ws + OFF_MT + (size_t)((st * 3 + i) * 8 + b) * 112 * 64 + ob;
#pragma unroll 1
        for (int k = 0; k < 112; ++k) {
            float pv = P[col * 113 + k];
            const float* mr = MTp + (size_t)k * 64;
#pragma unroll
            for (int j = 0; j < 32; ++j) acc[j] = fmaf(mr[j], pv, acc[j]);
        }
        __syncthreads();
    }
    const float* gin = (st ? c_in : g_in) + (size_t)b * 64 * NN + n0 + col;
    const float* AT = ws + OFF_AT + (size_t)st * 4096 + ob;
#pragma unroll 1
    for (int c = 0; c < 64; ++c) {
        float gv = gin[(size_t)c << 14];
        const float* ar = AT + (size_t)c * 64;
#pragma unroll
        for (int j = 0; j < 32; ++j) acc[j] = fmaf(ar[j], gv, acc[j]);
    }
    float* xf = ws + OFF_XF + (size_t)st * SZ_XF_ST + (size_t)b * 64 * NN + n0 + col;
#pragma unroll
    for (int j = 0; j < 32; ++j) {
        size_t o = (size_t)(ob + j);
        xf[o << 14] = tanhf(acc[j]) + gin[o << 14];
    }
}

// ---------------- t,p,g fields ----------------
__global__ __launch_bounds__(256) void k_tpg(float* __restrict__ ws) {
    __shared__ float X[64 * 65];
    const int tid = threadIdx.x;
    const int n0 = blockIdx.x << 6; const int b = blockIdx.y; const int f = blockIdx.z;
    const float* src = ws + OFF_XF + (f == 0 ? 0 : SZ_XF_ST) + (size_t)b * 64 * NN;
    for (int ff = tid; ff < 4096; ff += 256) {
        int c = ff >> 6; int nn2 = ff & 63;
        X[c * 65 + nn2] = src[((size_t)c << 14) + n0 + nn2];
    }
    __syncthreads();
    const int col = tid & 63; const int qg = __builtin_amdgcn_readfirstlane(tid >> 6);
    const float* WT = ws + OFF_WT + (size_t)f * 4096 + qg * 16;
    float acc[16];
#pragma unroll
    for (int j = 0; j < 16; ++j) acc[j] = 0.f;
#pragma unroll 1
    for (int c = 0; c < 64; ++c) {
        float xv = X[c * 65 + col];
        const float* wr = WT + (size_t)c * 64;
#pragma unroll
        for (int j = 0; j < 16; ++j) acc[j] = fmaf(wr[j], xv, acc[j]);
    }
    float* dst = ws + OFF_XQ + (size_t)f * SZ_XF_ST + (size_t)b * 64 * NN + n0 + col;
#pragma unroll
    for (int j = 0; j < 16; ++j) dst[(size_t)(qg * 16 + j) << 14] = acc[j];
}

// ---------------- attention coefficients per (b,g) ----------------
__global__ __launch_bounds__(256) void k_attred(float* __restrict__ ws) {
    __shared__ float r0[256], r1[256], r2[256];
    const int g = blockIdx.x, b = blockIdx.y, tid = threadIdx.x;
    const float* pf = ws + OFF_XQ + SZ_XF_ST + ((size_t)(b * 64 + g * 8) << 14);
    const float* gf = pf + SZ_XF_ST;
    float s0 = 0.f, s1 = 0.f, s2 = 0.f;
    for (int idx = tid; idx < 131072; idx += 256) {
        float pv = pf[idx], gv = gf[idx];
        s0 += gv; s1 = fmaf(pv, gv, s1); s2 = fmaf(pv * pv, gv, s2);
    }
    r0[tid] = s0; r1[tid] = s1; r2[tid] = s2;
    __syncthreads();
    for (int w = 128; w > 0; w >>= 1) {
        if (tid < w) { r0[tid] += r0[tid + w]; r1[tid] += r1[tid + w]; r2[tid] += r2[tid + w]; }
        __syncthreads();
    }
    if (tid == 0) {
        float* a = ws + OFF_ATTC + (size_t)(b * 8 + g) * 3;
        a[0] = A0SQ * r0[0]; a[1] = A1SQ * r1[0]; a[2] = A2SQ * r2[0];
    }
}

// ---------------- GroupNorm stats ----------------
__global__ __launch_bounds__(256) void k_stats(float* __restrict__ ws, const float* __restrict__ zw) {
    __shared__ float r0[256], r1[256];
    const int g = blockIdx.x, b = blockIdx.y, tid = threadIdx.x;
    const float* tf = ws + OFF_XQ + ((size_t)(b * 64 + g * 8) << 14);
    const float* a = ws + OFF_ATTC + (size_t)(b * 8 + g) * 3;
    const float c0 = a[0], c1 = a[1], c2 = a[2];
    const float* z = zw + (size_t)g * 64;
    float sum = 0.f, ssq = 0.f;
    for (int n = tid; n < 16384; n += 256) {
        float y[8];
#pragma unroll
        for (int pl = 0; pl < 8; ++pl) { float tv = tf[((size_t)pl << 14) + n]; y[pl] = fmaf(fmaf(c2, tv, c1), tv, c0); }
#pragma unroll
        for (int o = 0; o < 8; ++o) {
            float xz = 0.f;
#pragma unroll
            for (int i2 = 0; i2 < 8; ++i2) xz = fmaf(z[o * 8 + i2], y[i2], xz);
            sum += xz; ssq = fmaf(xz, xz, ssq);
        }
    }
    r0[tid] = sum; r1[tid] = ssq;
    __syncthreads();
    for (int w = 128; w > 0; w >>= 1) {
        if (tid < w) { r0[tid] += r0[tid + w]; r1[tid] += r1[tid + w]; }
        __syncthreads();
    }
    if (tid == 0) {
        float mean = r0[0] * (1.f / 131072.f);
        float var = r1[0] * (1.f / 131072.f) - mean * mean;
        float* mv = ws + OFF_MV + (size_t)(b * 8 + g) * 2;
        mv[0] = mean; mv[1] = rsqrtf(var + 1e-5f);
    }
}

// ---------------- final ----------------
__global__ __launch_bounds__(256) void k_final(float* __restrict__ ws, const float* __restrict__ zw,
                                               const float* __restrict__ gnw, const float* __restrict__ gnb,
                                               const float* __restrict__ g_in, float* __restrict__ out) {
    int id = blockIdx.x * 256 + threadIdx.x;
    int n = id & 16383; int g = (id >> 14) & 7; int b = id >> 17;
    const float* a = ws + OFF_ATTC + (size_t)(b * 8 + g) * 3;
    const float c0 = a[0], c1 = a[1], c2 = a[2];
    const float* mv = ws + OFF_MV + (size_t)(b * 8 + g) * 2;
    const float mean = mv[0], istd = mv[1];
    const float* z = zw + (size_t)g * 64;
    const float* tf = ws + OFF_XQ + ((size_t)(b * 64 + g * 8) << 14) + n;
    float y[8];
#pragma unroll
    for (int pl = 0; pl < 8; ++pl) { float tv = tf[(size_t)pl << 14]; y[pl] = fmaf(fmaf(c2, tv, c1), tv, c0); }
    const size_t cb = ((size_t)(b * 64 + g * 8) << 14) + n;
    const float* xg = ws + OFF_XF + cb;
    const float* gi = g_in + cb;
    float* op = out + cb;
#pragma unroll
    for (int o = 0; o < 8; ++o) {
        float xz = 0.f;
#pragma unroll
        for (int i2 = 0; i2 < 8; ++i2) xz = fmaf(z[o * 8 + i2], y[i2], xz);
        int ch = g * 8 + o;
        float v = fmaf((xz - mean) * istd, gnw[ch], gnb[ch]) + xg[(size_t)o << 14] + gi[(size_t)o << 14];
        op[(size_t)o << 14] = v;
    }
}

// ---------------- host launch ----------------
extern "C" void kernel_launch(void* const* d_in, const int* in_sizes, int n_in,
                              void* d_out, int out_size, void* d_ws, size_t ws_size,
                              hipStream_t stream) {
    const float* in_g = (const float*)d_in[0];
    const float* in_c = (const float*)d_in[1];
    float* ws = (float*)d_ws;
    float* out = (float*)d_out;

    ushort* xt_g = (ushort*)(ws + OFF_XF);
    ushort* xt_c = (ushort*)(ws + OFF_XF + 4194304);
    ushort* wt_g = (ushort*)(ws + OFF_XF + 8388608);
    ushort* wt_c = wt_g + 73728;

    // input transpose + weight re-layout (bf16)
    k_xt<<<dim3(128, 8), 256, 0, stream>>>(in_g, xt_g);
    k_xt<<<dim3(128, 8), 256, 0, stream>>>(in_c, xt_c);
    k_wt<<<576, 256, 0, stream>>>((const float*)d_in[20], (const float*)d_in[21], wt_g, wt_c);

    // MFMA convs -> xq regions (f32 output)
    k_convm<<<dim3(128, 8), 256, 0, stream>>>(xt_g, wt_g, ws + OFF_XQ);
    k_convm<<<dim3(128, 8), 256, 0, stream>>>(xt_c, wt_c, ws + OFF_XQ + SZ_XQ_ST);

    // pyramid pooling of raw features
    PoolPtrs pp;
    pp.src[0] = (const float*)d_in[3];  pp.src[1] = (const float*)d_in[9];  pp.src[2] = (const float*)d_in[15];
    pp.src[3] = (const float*)d_in[2];  pp.src[4] = (const float*)d_in[8];  pp.src[5] = (const float*)d_in[14];
    k_pool<<<7168, 256, 128 * 129 * 4, stream>>>(pp, ws);

    // weight precomputes
    k_pkw<<<368, 256, 0, stream>>>((const float*)d_in[24], (const float*)d_in[25],
                                   (const float*)d_in[22], (const float*)d_in[23],
                                   (const float*)d_in[26], (const float*)d_in[27],
                                   (const float*)d_in[28], ws);

    // xk, xv
    KvPtrs kp;
    kp.k1[0] = (const float*)d_in[4];  kp.k1[1] = (const float*)d_in[10]; kp.k1[2] = (const float*)d_in[16];
    kp.k2[0] = (const float*)d_in[6];  kp.k2[1] = (const float*)d_in[12]; kp.k2[2] = (const float*)d_in[18];
    kp.v1[0] = (const float*)d_in[5];  kp.v1[1] = (const float*)d_in[11]; kp.v1[2] = (const float*)d_in[17];
    kp.v2[0] = (const float*)d_in[7];  kp.v2[1] = (const float*)d_in[13]; kp.v2[2] = (const float*)d_in[19];
    k_xkxv<<<5376, 256, 0, stream>>>(kp, ws);

    // M_T
    k_mt<<<1344, 256, 0, stream>>>(ws);

    // fused attention -> x_gray / x_color (overwrites Xt/Wt staging — OK, convs done)
    k_attn<<<dim3(256, 8, 2), 128, 0, stream>>>(ws, in_g, in_c);

    // t,p,g fields (reuse xq region)
    k_tpg<<<dim3(256, 8, 3), 256, 0, stream>>>(ws);

    // attention coefficients, GN stats, final
    k_attred<<<dim3(8, 8), 256, 0, stream>>>(ws);
    k_stats<<<dim3(8, 8), 256, 0, stream>>>(ws, (const float*)d_in[29]);
    k_final<<<4096, 256, 0, stream>>>(ws, (const float*)d_in[29], (const float*)d_in[30],
                                      (const float*)d_in[31], in_g, out);
}

// Round 3
// 904.250 us; speedup vs baseline: 4.2476x; 1.8840x over previous
//
#include <hip/hip_runtime.h>
#include <math.h>

// ---------------- problem constants ----------------
// B=8, CIN=64, H=W=128, N=16384, IC=128, P=110 (padded 112/128), FN=3
constexpr int    BB      = 8;
constexpr int    NN      = 16384;
constexpr size_t SZ_XQ_ST = (size_t)BB * 128 * NN;      // 16,777,216 floats
constexpr size_t SZ_XF_ST = (size_t)BB * 64 * NN;       //  8,388,608 floats

// float-slot offsets in ws
constexpr size_t OFF_XQ   = 0;                          // xqb bf16 [2][8][16384][128] (16,777,216 slots); later t/p/g f32 reuse
constexpr size_t OFF_XT   = 16777216;                   // Xt bf16 [2][8][16384][64]  (8,388,608 slots)
constexpr size_t OFF_XF   = 33554432;                   // x_gray,x_color f32 (2*SZ_XF_ST); Wt staging early
constexpr size_t OFF_POOL = OFF_XF + 2 * SZ_XF_ST;      // 50,331,648 : pooled feats f32 (788,480)
constexpr size_t OFF_XK   = OFF_POOL + 788480;          // 51,120,128 : xkb bf16 [48][112][128] (344,064 slots)
constexpr size_t OFF_XV   = OFF_XK + 344064;            // 51,464,192 : xv f32 [48][128][112] (688,128)
constexpr size_t OFF_MT   = OFF_XV + 688128;            // 52,152,320 : MTb bf16 [48][64][128] (393,216 slots)
constexpr size_t OFF_W    = OFF_MT + 393216;            // 52,545,536 : W f32 [2][3][64][192] (73,728)
constexpr size_t OFF_AT   = OFF_W + 73728;              // 52,619,264 : ATb bf16 [2][64][64] (4,096 slots)
constexpr size_t OFF_WT   = OFF_AT + 4096;              // 52,623,360 : t/p/g wT f32 [3][64][64] (12,288)
constexpr size_t OFF_ATTC = OFF_WT + 12288;             // 52,635,648 : [8][8][3]
constexpr size_t OFF_MV   = OFF_ATTC + 192;             // 52,635,840 : [8][8][2]
// end = 52,636,032 floats = 210.5 MiB

#define A0SQ 0.9998000199986667f
#define A1SQ 1.9996000399973335e-4f
#define A2SQ 1.9996000399973334e-8f

typedef __attribute__((ext_vector_type(8))) short bf16x8;
typedef __attribute__((ext_vector_type(4))) float f32x4;

__device__ inline ushort f2bf(float f) {
    uint u = __float_as_uint(f);
    return (ushort)((u + 0x7fffu + ((u >> 16) & 1u)) >> 16);
}

// ---------------- input transpose: f32 [64][128][128] -> bf16 [y][x][64] ----------------
__global__ __launch_bounds__(256) void k_xt(const float* __restrict__ in, ushort* __restrict__ xt) {
    __shared__ float L[64 * 130];
    const int y = blockIdx.x, b = blockIdx.y, tid = threadIdx.x;
    const float* ib = in + (((size_t)b * 64) << 14) + (y << 7);
    for (int r = 0; r < 32; ++r) {
        int idx = tid + (r << 8); int ch = idx >> 7; int x = idx & 127;
        L[ch * 130 + x] = ib[((size_t)ch << 14) + x];
    }
    __syncthreads();
    const int x = tid >> 1, seg = tid & 1;
    ushort* ob = xt + ((size_t)(b * 128 + y) * 128 + x) * 64 + seg * 32;
    uint pk[16];
#pragma unroll
    for (int c = 0; c < 16; ++c) {
        uint lo = f2bf(L[(seg * 32 + 2 * c) * 130 + x]);
        uint hi = f2bf(L[(seg * 32 + 2 * c + 1) * 130 + x]);
        pk[c] = lo | (hi << 16);
    }
    uint4* o4 = (uint4*)ob;
#pragma unroll
    for (int c = 0; c < 4; ++c) o4[c] = make_uint4(pk[4 * c], pk[4 * c + 1], pk[4 * c + 2], pk[4 * c + 3]);
}

// ---------------- weight re-layout: f32 [oc][ic][3][3] -> bf16 [t][oc][ic] ----------------
__global__ __launch_bounds__(256) void k_wt(const float* __restrict__ w1, const float* __restrict__ w2,
                                            ushort* __restrict__ wt1, ushort* __restrict__ wt2) {
    int id = blockIdx.x * 256 + threadIdx.x;
    if (id >= 147456) return;
    int cs = id / 73728; int rem = id - cs * 73728;
    int t = rem >> 13; int oc = (rem >> 6) & 127; int ic = rem & 63;
    const float* w = cs ? w2 : w1;
    (cs ? wt2 : wt1)[rem] = f2bf(w[((size_t)(oc * 64 + ic)) * 9 + t]);
}

// ---------------- conv 3x3 SAME 64->128 bf16 MFMA; output bf16 [n][128c] ----------------
__global__ __launch_bounds__(256) void k_convm(const ushort* __restrict__ Xt, const ushort* __restrict__ Wt,
                                               ushort* __restrict__ out) {
    __shared__ ushort smem[2 * 128 * 72];               // 36,864 B
    ushort* lds_w = smem;
    ushort* lds_x = smem + 128 * 72;
    const int tid = threadIdx.x;
    const int y = blockIdx.x, b = blockIdx.y;
    const int l = tid & 63;
    const int wv = __builtin_amdgcn_readfirstlane(tid >> 6);
    const int lr = l & 15;
    const int q = l >> 4;
    const int cr = tid >> 1;
    const int seg = tid & 1;

    f32x4 acc[2][8];
#pragma unroll
    for (int f = 0; f < 2; ++f)
#pragma unroll
        for (int g = 0; g < 8; ++g)
#pragma unroll
            for (int r = 0; r < 4; ++r) acc[f][g][r] = 0.f;

#pragma unroll 1
    for (int t = 0; t < 9; ++t) {
        const int dy = t / 3, dx = t - dy * 3;
        const int srow = y + dy - 1;
        {
            const uint4* s = (const uint4*)(Wt + ((size_t)(t * 128 + cr) * 64 + seg * 32));
            uint4* d = (uint4*)(lds_w + cr * 72 + seg * 32);
            d[0] = s[0]; d[1] = s[1]; d[2] = s[2]; d[3] = s[3];
        }
        {
            const int sx = cr + dx - 1;
            const bool v = (srow >= 0) & (srow < 128) & (sx >= 0) & (sx < 128);
            const uint4* s = (const uint4*)(Xt + (((size_t)(b * 128 + srow) * 128 + sx) * 64 + seg * 32));
            uint4 z = make_uint4(0, 0, 0, 0);
            uint4 r0 = v ? s[0] : z, r1 = v ? s[1] : z, r2 = v ? s[2] : z, r3 = v ? s[3] : z;
            uint4* d = (uint4*)(lds_x + cr * 72 + seg * 32);
            d[0] = r0; d[1] = r1; d[2] = r2; d[3] = r3;
        }
        __syncthreads();
#pragma unroll
        for (int h = 0; h < 2; ++h) {
            const int ko = h * 32 + q * 8;
            bf16x8 a0 = *(const bf16x8*)(lds_w + (wv * 32 + lr) * 72 + ko);
            bf16x8 a1 = *(const bf16x8*)(lds_w + (wv * 32 + 16 + lr) * 72 + ko);
#pragma unroll
            for (int g = 0; g < 8; ++g) {
                bf16x8 bb = *(const bf16x8*)(lds_x + (g * 16 + lr) * 72 + ko);
                acc[0][g] = __builtin_amdgcn_mfma_f32_16x16x32_bf16(a0, bb, acc[0][g], 0, 0, 0);
                acc[1][g] = __builtin_amdgcn_mfma_f32_16x16x32_bf16(a1, bb, acc[1][g], 0, 0, 0);
            }
        }
        __syncthreads();
    }
    // epilogue: transpose to [x][oc] bf16 via LDS, write xqb[n][c] coalesced
    uint* T = (uint*)smem;                              // 128 rows x 68 dwords
#pragma unroll
    for (int f = 0; f < 2; ++f)
#pragma unroll
        for (int g = 0; g < 8; ++g) {
            uint lo = (uint)f2bf(acc[f][g][0]) | ((uint)f2bf(acc[f][g][1]) << 16);
            uint hi = (uint)f2bf(acc[f][g][2]) | ((uint)f2bf(acc[f][g][3]) << 16);
            int dw = (g * 16 + lr) * 68 + wv * 16 + f * 8 + q * 2;
            T[dw] = lo; T[dw + 1] = hi;
        }
    __syncthreads();
    const int x = tid >> 1, sg = tid & 1;
    ushort* ob = out + ((size_t)(b * 128 + y) * 128 + x) * 128 + sg * 64;
    const uint* src = &T[x * 68 + sg * 32];
#pragma unroll
    for (int j = 0; j < 8; ++j) {
        uint4 vv = *(const uint4*)(src + 4 * j);
        *(uint4*)(ob + j * 8) = vv;
    }
}

// ---------------- pyramid pooling via 2D prefix sums ----------------
struct PoolPtrs { const float* src[6]; };

__global__ __launch_bounds__(256) void k_pool(PoolPtrs pp, float* __restrict__ ws) {
    extern __shared__ float P[];
    const int plane = blockIdx.x;
    const int tid = threadIdx.x;
    int tI, h; size_t toff; int base;
    if      (plane < 512)  { tI = 0; h = 128; toff = 0;      base = 0;    }
    else if (plane < 1536) { tI = 1; h = 64;  toff = 56320;  base = 512;  }
    else if (plane < 3584) { tI = 2; h = 32;  toff = 168960; base = 1536; }
    else if (plane < 4096) { tI = 3; h = 128; toff = 394240; base = 3584; }
    else if (plane < 5120) { tI = 4; h = 64;  toff = 450560; base = 4096; }
    else                   { tI = 5; h = 32;  toff = 563200; base = 5120; }
    const int local = plane - base;
    const float* img = pp.src[tI] + (size_t)local * h * h;
    const int stride = h + 1;
    const int hh = h * h;
    for (int f = tid; f < hh; f += 256) {
        int r = f / h; int cc = f - r * h;
        P[r * stride + cc] = img[f];
    }
    __syncthreads();
    if (tid < h) {
        float cur = 0.f; const int rb = tid * stride;
        for (int cc = 0; cc < h; ++cc) { cur += P[rb + cc]; P[rb + cc] = cur; }
    }
    __syncthreads();
    if (tid < h) {
        float cur = 0.f;
        for (int r = 0; r < h; ++r) { int a = r * stride + tid; cur += P[a]; P[a] = cur; }
    }
    __syncthreads();
    if (tid < 110) {
        int s, off2;
        if (tid == 0)      { s = 1; off2 = 0; }
        else if (tid < 10) { s = 3; off2 = 1; }
        else if (tid < 46) { s = 6; off2 = 10; }
        else               { s = 8; off2 = 46; }
        int r = tid - off2; int j = r / s; int q = r - j * s;
        const int n = h + 2;
        int ra = (j * n) / s,       rb2 = ((j + 1) * n + s - 1) / s;
        int ca = (q * n) / s,       cb2 = ((q + 1) * n + s - 1) / s;
        float area = (float)((rb2 - ra) * (cb2 - ca));
        int r0 = ra - 1; if (r0 < 0) r0 = 0;  int r1 = rb2 - 1; if (r1 > h) r1 = h;
        int c0 = ca - 1; if (c0 < 0) c0 = 0;  int c1 = cb2 - 1; if (c1 > h) c1 = h;
        float ssum = 0.f;
        if (r1 > r0 && c1 > c0) {
            int ri = r1 - 1, rj = r0 - 1, ci = c1 - 1, cj = c0 - 1;
            float f11 = P[ri * stride + ci];
            float f01 = (rj < 0) ? 0.f : P[rj * stride + ci];
            float f10 = (cj < 0) ? 0.f : P[ri * stride + cj];
            float f00 = (rj < 0 || cj < 0) ? 0.f : P[rj * stride + cj];
            ssum = f11 - f01 - f10 + f00;
        }
        ws[OFF_POOL + toff + (size_t)local * 110 + tid] = ssum / area;
    }
}

// ---------------- small weight precomputes ----------------
__global__ __launch_bounds__(256) void k_pkw(const float* __restrict__ f1, const float* __restrict__ f2,
                                             const float* __restrict__ m1, const float* __restrict__ m2,
                                             const float* __restrict__ tw, const float* __restrict__ pw,
                                             const float* __restrict__ gw, float* __restrict__ ws) {
    int id = blockIdx.x * 256 + threadIdx.x;
    if (id < 73728) {                                   // W[st][i][o][c]
        int c = id % 192; int t = id / 192; int o = t & 63; int t2 = t >> 6; int i = t2 % 3; int st = t2 / 3;
        const float* fu = st ? f2 : f1; const float* ma = st ? m2 : m1;
        float s = 0.f;
        for (int k = 0; k < 64; ++k) s = fmaf(fu[o * 192 + i * 64 + k], ma[k * 192 + c], s);
        ws[OFF_W + id] = s;
    } else if (id < 81920) {                            // ATb bf16 [st][o][c]
        int x = id - 73728; int o = x & 63; int c = (x >> 6) & 63; int st = x >> 12;
        const float* fu = st ? f2 : f1; const float* ma = st ? m2 : m1;
        float s = 0.f;
        for (int k = 0; k < 192; ++k) s = fmaf(fu[o * 192 + k], ma[(k & 63) * 192 + c], s);
        ((ushort*)(ws + OFF_AT))[(size_t)st * 4096 + o * 64 + c] = f2bf(s);
    } else if (id < 94208) {                            // WT f32 [f][c][o]
        int x = id - 81920; int o = x & 63; int c = (x >> 6) & 63; int f = x >> 12;
        const float* src = (f == 0) ? tw : ((f == 1) ? pw : gw);
        ws[OFF_WT + (size_t)f * 4096 + c * 64 + o] = src[o * 64 + c];
    }
}

// ---------------- xk (bf16 [p][c]) / xv (f32 [c][p]) from pooled features ----------------
struct KvPtrs { const float* k1[3]; const float* k2[3]; const float* v1[3]; const float* v2[3]; };

__global__ __launch_bounds__(256) void k_xkxv(KvPtrs kp, float* __restrict__ ws) {
    int id = blockIdx.x * 256 + threadIdx.x;
    int isV = 0;
    if (id >= 688128) { isV = 1; id -= 688128; }
    int p = id % 112; int t1 = id / 112; int C = t1 & 127; int t2 = t1 >> 7;
    int b = t2 & 7; int t3 = t2 >> 3; int i = t3 % 3; int st = t3 / 3;
    const int ci = 64 << i;
    size_t poff = (size_t)st * 394240 + (i >= 1 ? 56320 : 0) + (i >= 2 ? 112640 : 0);
    const float* kw = isV ? (st ? kp.v2[i] : kp.v1[i]) : (st ? kp.k2[i] : kp.k1[i]);
    float s = 0.f;
    if (p < 110) {
        const float* pl = ws + OFF_POOL + poff + (size_t)b * ci * 110 + p;
        for (int ic = 0; ic < ci; ++ic) s = fmaf(kw[C * ci + ic], pl[(size_t)ic * 110], s);
    }
    if (isV) ws[OFF_XV + id] = s;
    else     ((ushort*)(ws + OFF_XK))[(size_t)t2 * 14336 + p * 128 + C] = f2bf(s);
}

// ---------------- MTb bf16 [t2][o][p(128, zero-pad)] ----------------
__global__ __launch_bounds__(256) void k_mt(float* __restrict__ ws) {
    int id = blockIdx.x * 256 + threadIdx.x;            // 786,432
    int p = id & 127; int o = (id >> 7) & 63; int t2 = id >> 13;
    int sti = t2 >> 3;
    float s = 0.f;
    if (p < 110) {
        const float* Wrow = ws + OFF_W + ((size_t)sti * 64 + o) * 192 + 64;
        const float* xv = ws + OFF_XV + (size_t)t2 * 128 * 112 + p;
        for (int r = 0; r < 128; ++r) s = fmaf(Wrow[r], xv[(size_t)r * 112], s);
    }
    ((ushort*)(ws + OFF_MT))[id] = f2bf(s);
}

// ---------------- fused MFMA attention ----------------
// block: 256 thr / 4 waves; 128 cols; wave w owns N-tiles {2w, 2w+1}
__global__ __launch_bounds__(256) void k_attn2(float* __restrict__ ws,
                                               const float* __restrict__ g_in,
                                               const float* __restrict__ c_in) {
    __shared__ uint pbuf[128 * 68];                     // P bf16 [n][128p], pitch 68 dwords
    const int tid = threadIdx.x;
    const int w = __builtin_amdgcn_readfirstlane(tid >> 6);
    const int l = tid & 63;
    const int lr = l & 15;
    const int g4 = l >> 4;
    const int n0 = blockIdx.x << 7;
    const int b = blockIdx.y;
    const int st = blockIdx.z;

    const ushort* xqb = (const ushort*)(ws + OFF_XQ);
    const ushort* xkb = (const ushort*)(ws + OFF_XK);
    const ushort* mtb = (const ushort*)(ws + OFF_MT);
    const ushort* atb = (const ushort*)(ws + OFF_AT);
    const ushort* xt  = (const ushort*)(ws + OFF_XT) + (size_t)st * 8388608;

    // zero p=112..127 pad in this wave's rows
    {
        int row = 32 * w + (l >> 1);
        int dcol = 56 + ((l & 1) << 2);
#pragma unroll
        for (int j = 0; j < 4; ++j) pbuf[row * 68 + dcol + j] = 0;
    }

    // persistent xq B fragments
    bf16x8 bq[2][4];
    const ushort* xq_base = xqb + ((size_t)(st * 8 + b) * 16384 + n0) * 128;
#pragma unroll
    for (int nt = 0; nt < 2; ++nt)
#pragma unroll
        for (int kk = 0; kk < 4; ++kk)
            bq[nt][kk] = *(const bf16x8*)(xq_base + (size_t)((2 * w + nt) * 16 + lr) * 128 + kk * 32 + g4 * 8);

    f32x4 pacc[4][2];
#pragma unroll
    for (int m = 0; m < 4; ++m)
#pragma unroll
        for (int nt = 0; nt < 2; ++nt)
#pragma unroll
            for (int r = 0; r < 4; ++r) pacc[m][nt][r] = 0.f;

    // residual-matrix term: A(64x64) @ in(64xN)
#pragma unroll
    for (int kk = 0; kk < 2; ++kk) {
        bf16x8 bi[2];
#pragma unroll
        for (int nt = 0; nt < 2; ++nt)
            bi[nt] = *(const bf16x8*)(xt + ((size_t)b * 16384 + n0 + (2 * w + nt) * 16 + lr) * 64 + kk * 32 + g4 * 8);
#pragma unroll
        for (int m = 0; m < 4; ++m) {
            bf16x8 a = *(const bf16x8*)(atb + (size_t)st * 4096 + (m * 16 + lr) * 64 + kk * 32 + g4 * 8);
#pragma unroll
            for (int nt = 0; nt < 2; ++nt)
                pacc[m][nt] = __builtin_amdgcn_mfma_f32_16x16x32_bf16(a, bi[nt], pacc[m][nt], 0, 0, 0);
        }
    }

#pragma unroll 1
    for (int i = 0; i < 3; ++i) {
        const ushort* xk = xkb + (size_t)((st * 3 + i) * 8 + b) * 14336;
        const ushort* mt_p = mtb + (size_t)((st * 3 + i) * 8 + b) * 8192;
        f32x4 sacc[7][2];
#pragma unroll
        for (int m = 0; m < 7; ++m)
#pragma unroll
            for (int nt = 0; nt < 2; ++nt)
#pragma unroll
                for (int r = 0; r < 4; ++r) sacc[m][nt][r] = 0.f;
        // S = xk^T @ xq
#pragma unroll
        for (int kk = 0; kk < 4; ++kk) {
            bf16x8 a[7];
#pragma unroll
            for (int m = 0; m < 7; ++m)
                a[m] = *(const bf16x8*)(xk + (size_t)(m * 16 + lr) * 128 + kk * 32 + g4 * 8);
#pragma unroll
            for (int m = 0; m < 7; ++m)
#pragma unroll
                for (int nt = 0; nt < 2; ++nt)
                    sacc[m][nt] = __builtin_amdgcn_mfma_f32_16x16x32_bf16(a[m], bq[nt][kk], sacc[m][nt], 0, 0, 0);
        }
        // in-register softmax over p (per column), mask p>=110, clip +-64
#pragma unroll
        for (int nt = 0; nt < 2; ++nt) {
            float mx = -3.0e38f;
#pragma unroll
            for (int m = 0; m < 7; ++m)
#pragma unroll
                for (int r = 0; r < 4; ++r) {
                    int p = m * 16 + g4 * 4 + r;
                    float s = fminf(fmaxf(sacc[m][nt][r], -64.f), 64.f);
                    if (p >= 110) s = -3.0e38f;
                    sacc[m][nt][r] = s;
                    mx = fmaxf(mx, s);
                }
            mx = fmaxf(mx, __shfl_xor(mx, 16));
            mx = fmaxf(mx, __shfl_xor(mx, 32));
            float sum = 0.f;
#pragma unroll
            for (int m = 0; m < 7; ++m)
#pragma unroll
                for (int r = 0; r < 4; ++r) {
                    float e = __expf(sacc[m][nt][r] - mx);
                    sacc[m][nt][r] = e;
                    sum += e;
                }
            sum += __shfl_xor(sum, 16);
            sum += __shfl_xor(sum, 32);
            float inv = 1.f / sum;
            int nloc = (2 * w + nt) * 16 + lr;
#pragma unroll
            for (int m = 0; m < 7; ++m) {
                uint lo = (uint)f2bf(sacc[m][nt][0] * inv) | ((uint)f2bf(sacc[m][nt][1] * inv) << 16);
                uint hi = (uint)f2bf(sacc[m][nt][2] * inv) | ((uint)f2bf(sacc[m][nt][3] * inv) << 16);
                int dw = nloc * 68 + m * 8 + g4 * 2;
                pbuf[dw] = lo; pbuf[dw + 1] = hi;
            }
        }
        __syncthreads();
        // PV: out += MT^T(64x112) @ P(112xN)
#pragma unroll
        for (int kk = 0; kk < 4; ++kk) {
            bf16x8 am[4];
#pragma unroll
            for (int m = 0; m < 4; ++m)
                am[m] = *(const bf16x8*)(mt_p + (size_t)(m * 16 + lr) * 128 + kk * 32 + g4 * 8);
#pragma unroll
            for (int nt = 0; nt < 2; ++nt) {
                int nloc = (2 * w + nt) * 16 + lr;
                bf16x8 pb = *(const bf16x8*)((const ushort*)pbuf + (size_t)nloc * 136 + kk * 32 + g4 * 8);
#pragma unroll
                for (int m = 0; m < 4; ++m)
                    pacc[m][nt] = __builtin_amdgcn_mfma_f32_16x16x32_bf16(am[m], pb, pacc[m][nt], 0, 0, 0);
            }
        }
        __syncthreads();
    }
    // epilogue: xf = tanh(acc) + in
    const float* gin = (st ? c_in : g_in) + ((size_t)b * 64 << 14);
    float* xf = ws + OFF_XF + (size_t)st * SZ_XF_ST + ((size_t)b * 64 << 14);
#pragma unroll
    for (int m = 0; m < 4; ++m)
#pragma unroll
        for (int nt = 0; nt < 2; ++nt)
#pragma unroll
            for (int r = 0; r < 4; ++r) {
                int o = m * 16 + g4 * 4 + r;
                int n = n0 + (2 * w + nt) * 16 + lr;
                size_t idx = ((size_t)o << 14) + n;
                xf[idx] = tanhf(pacc[m][nt][r]) + gin[idx];
            }
}

// ---------------- t,p,g fields ----------------
__global__ __launch_bounds__(256) void k_tpg(float* __restrict__ ws) {
    __shared__ float X[64 * 65];
    const int tid = threadIdx.x;
    const int n0 = blockIdx.x << 6; const int b = blockIdx.y; const int f = blockIdx.z;
    const float* src = ws + OFF_XF + (f == 0 ? 0 : SZ_XF_ST) + (size_t)b * 64 * NN;
    for (int ff = tid; ff < 4096; ff += 256) {
        int c = ff >> 6; int nn2 = ff & 63;
        X[c * 65 + nn2] = src[((size_t)c << 14) + n0 + nn2];
    }
    __syncthreads();
    const int col = tid & 63; const int qg = __builtin_amdgcn_readfirstlane(tid >> 6);
    const float* WT = ws + OFF_WT + (size_t)f * 4096 + qg * 16;
    float acc[16];
#pragma unroll
    for (int j = 0; j < 16; ++j) acc[j] = 0.f;
#pragma unroll 1
    for (int c = 0; c < 64; ++c) {
        float xv = X[c * 65 + col];
        const float* wr = WT + (size_t)c * 64;
#pragma unroll
        for (int j = 0; j < 16; ++j) acc[j] = fmaf(wr[j], xv, acc[j]);
    }
    float* dst = ws + OFF_XQ + (size_t)f * SZ_XF_ST + (size_t)b * 64 * NN + n0 + col;
#pragma unroll
    for (int j = 0; j < 16; ++j) dst[(size_t)(qg * 16 + j) << 14] = acc[j];
}

// ---------------- attention coefficients per (b,g) ----------------
__global__ __launch_bounds__(256) void k_attred(float* __restrict__ ws) {
    __shared__ float r0[256], r1[256], r2[256];
    const int g = blockIdx.x, b = blockIdx.y, tid = threadIdx.x;
    const float* pf = ws + OFF_XQ + SZ_XF_ST + ((size_t)(b * 64 + g * 8) << 14);
    const float* gf = pf + SZ_XF_ST;
    float s0 = 0.f, s1 = 0.f, s2 = 0.f;
    for (int idx = tid; idx < 131072; idx += 256) {
        float pv = pf[idx], gv = gf[idx];
        s0 += gv; s1 = fmaf(pv, gv, s1); s2 = fmaf(pv * pv, gv, s2);
    }
    r0[tid] = s0; r1[tid] = s1; r2[tid] = s2;
    __syncthreads();
    for (int w = 128; w > 0; w >>= 1) {
        if (tid < w) { r0[tid] += r0[tid + w]; r1[tid] += r1[tid + w]; r2[tid] += r2[tid + w]; }
        __syncthreads();
    }
    if (tid == 0) {
        float* a = ws + OFF_ATTC + (size_t)(b * 8 + g) * 3;
        a[0] = A0SQ * r0[0]; a[1] = A1SQ * r1[0]; a[2] = A2SQ * r2[0];
    }
}

// ---------------- GroupNorm stats ----------------
__global__ __launch_bounds__(256) void k_stats(float* __restrict__ ws, const float* __restrict__ zw) {
    __shared__ float r0[256], r1[256];
    const int g = blockIdx.x, b = blockIdx.y, tid = threadIdx.x;
    const float* tf = ws + OFF_XQ + ((size_t)(b * 64 + g * 8) << 14);
    const float* a = ws + OFF_ATTC + (size_t)(b * 8 + g) * 3;
    const float c0 = a[0], c1 = a[1], c2 = a[2];
    const float* z = zw + (size_t)g * 64;
    float sum = 0.f, ssq = 0.f;
    for (int n = tid; n < 16384; n += 256) {
        float y[8];
#pragma unroll
        for (int pl = 0; pl < 8; ++pl) { float tv = tf[((size_t)pl << 14) + n]; y[pl] = fmaf(fmaf(c2, tv, c1), tv, c0); }
#pragma unroll
        for (int o = 0; o < 8; ++o) {
            float xz = 0.f;
#pragma unroll
            for (int i2 = 0; i2 < 8; ++i2) xz = fmaf(z[o * 8 + i2], y[i2], xz);
            sum += xz; ssq = fmaf(xz, xz, ssq);
        }
    }
    r0[tid] = sum; r1[tid] = ssq;
    __syncthreads();
    for (int w = 128; w > 0; w >>= 1) {
        if (tid < w) { r0[tid] += r0[tid + w]; r1[tid] += r1[tid + w]; }
        __syncthreads();
    }
    if (tid == 0) {
        float mean = r0[0] * (1.f / 131072.f);
        float var = r1[0] * (1.f / 131072.f) - mean * mean;
        float* mv = ws + OFF_MV + (size_t)(b * 8 + g) * 2;
        mv[0] = mean; mv[1] = rsqrtf(var + 1e-5f);
    }
}

// ---------------- final ----------------
__global__ __launch_bounds__(256) void k_final(float* __restrict__ ws, const float* __restrict__ zw,
                                               const float* __restrict__ gnw, const float* __restrict__ gnb,
                                               const float* __restrict__ g_in, float* __restrict__ out) {
    int id = blockIdx.x * 256 + threadIdx.x;
    int n = id & 16383; int g = (id >> 14) & 7; int b = id >> 17;
    const float* a = ws + OFF_ATTC + (size_t)(b * 8 + g) * 3;
    const float c0 = a[0], c1 = a[1], c2 = a[2];
    const float* mv = ws + OFF_MV + (size_t)(b * 8 + g) * 2;
    const float mean = mv[0], istd = mv[1];
    const float* z = zw + (size_t)g * 64;
    const float* tf = ws + OFF_XQ + ((size_t)(b * 64 + g * 8) << 14) + n;
    float y[8];
#pragma unroll
    for (int pl = 0; pl < 8; ++pl) { float tv = tf[(size_t)pl << 14]; y[pl] = fmaf(fmaf(c2, tv, c1), tv, c0); }
    const size_t cb = ((size_t)(b * 64 + g * 8) << 14) + n;
    const float* xg = ws + OFF_XF + cb;
    const float* gi = g_in + cb;
    float* op = out + cb;
#pragma unroll
    for (int o = 0; o < 8; ++o) {
        float xz = 0.f;
#pragma unroll
        for (int i2 = 0; i2 < 8; ++i2) xz = fmaf(z[o * 8 + i2], y[i2], xz);
        int ch = g * 8 + o;
        float v = fmaf((xz - mean) * istd, gnw[ch], gnb[ch]) + xg[(size_t)o << 14] + gi[(size_t)o << 14];
        op[(size_t)o << 14] = v;
    }
}

// ---------------- host launch ----------------
extern "C" void kernel_launch(void* const* d_in, const int* in_sizes, int n_in,
                              void* d_out, int out_size, void* d_ws, size_t ws_size,
                              hipStream_t stream) {
    const float* in_g = (const float*)d_in[0];
    const float* in_c = (const float*)d_in[1];
    float* ws = (float*)d_ws;
    float* out = (float*)d_out;

    ushort* xqb  = (ushort*)(ws + OFF_XQ);
    ushort* xt_g = (ushort*)(ws + OFF_XT);
    ushort* xt_c = xt_g + 8388608;
    ushort* wt_g = (ushort*)(ws + OFF_XF);
    ushort* wt_c = wt_g + 73728;

    // input transpose + weight re-layout (bf16)
    k_xt<<<dim3(128, 8), 256, 0, stream>>>(in_g, xt_g);
    k_xt<<<dim3(128, 8), 256, 0, stream>>>(in_c, xt_c);
    k_wt<<<576, 256, 0, stream>>>((const float*)d_in[20], (const float*)d_in[21], wt_g, wt_c);

    // MFMA convs -> xqb bf16 [n][c] slabs
    k_convm<<<dim3(128, 8), 256, 0, stream>>>(xt_g, wt_g, xqb);
    k_convm<<<dim3(128, 8), 256, 0, stream>>>(xt_c, wt_c, xqb + 16777216);

    // pyramid pooling of raw features
    PoolPtrs pp;
    pp.src[0] = (const float*)d_in[3];  pp.src[1] = (const float*)d_in[9];  pp.src[2] = (const float*)d_in[15];
    pp.src[3] = (const float*)d_in[2];  pp.src[4] = (const float*)d_in[8];  pp.src[5] = (const float*)d_in[14];
    k_pool<<<7168, 256, 128 * 129 * 4, stream>>>(pp, ws);

    // weight precomputes
    k_pkw<<<368, 256, 0, stream>>>((const float*)d_in[24], (const float*)d_in[25],
                                   (const float*)d_in[22], (const float*)d_in[23],
                                   (const float*)d_in[26], (const float*)d_in[27],
                                   (const float*)d_in[28], ws);

    // xk (bf16), xv (f32)
    KvPtrs kp;
    kp.k1[0] = (const float*)d_in[4];  kp.k1[1] = (const float*)d_in[10]; kp.k1[2] = (const float*)d_in[16];
    kp.k2[0] = (const float*)d_in[6];  kp.k2[1] = (const float*)d_in[12]; kp.k2[2] = (const float*)d_in[18];
    kp.v1[0] = (const float*)d_in[5];  kp.v1[1] = (const float*)d_in[11]; kp.v1[2] = (const float*)d_in[17];
    kp.v2[0] = (const float*)d_in[7];  kp.v2[1] = (const float*)d_in[13]; kp.v2[2] = (const float*)d_in[19];
    k_xkxv<<<5376, 256, 0, stream>>>(kp, ws);

    // MTb bf16
    k_mt<<<3072, 256, 0, stream>>>(ws);

    // fused MFMA attention -> x_gray / x_color
    k_attn2<<<dim3(128, 8, 2), 256, 0, stream>>>(ws, in_g, in_c);

    // t,p,g fields (reuse xq region)
    k_tpg<<<dim3(256, 8, 3), 256, 0, stream>>>(ws);

    // attention coefficients, GN stats, final
    k_attred<<<dim3(8, 8), 256, 0, stream>>>(ws);
    k_stats<<<dim3(8, 8), 256, 0, stream>>>(ws, (const float*)d_in[29]);
    k_final<<<4096, 256, 0, stream>>>(ws, (const float*)d_in[29], (const float*)d_in[30],
                                      (const float*)d_in[31], in_g, out);
}

// Round 4
// 673.409 us; speedup vs baseline: 5.7037x; 1.3428x over previous
//
#include <hip/hip_runtime.h>
#include <math.h>

// ---------------- problem constants ----------------
// B=8, CIN=64, H=W=128, N=16384, IC=128, P=110 (padded 112/128), FN=3
constexpr int    BB      = 8;
constexpr int    NN      = 16384;
constexpr size_t SZ_XQ_ST = (size_t)BB * 128 * NN;      // 16,777,216 floats
constexpr size_t SZ_XF_ST = (size_t)BB * 64 * NN;       //  8,388,608 floats

// float-slot offsets in ws
constexpr size_t OFF_XQ   = 0;                          // xqb bf16 [2][8][16384][128]; later t-field f32 reuse
constexpr size_t OFF_XT   = 16777216;                   // Xt bf16 [2][8][16384][64]
constexpr size_t OFF_XF   = 33554432;                   // x_gray,x_color f32 (2*SZ_XF_ST); Wt staging early
constexpr size_t OFF_POOL = OFF_XF + 2 * SZ_XF_ST;      // pooled feats f32 (788,480)
constexpr size_t OFF_XK   = OFF_POOL + 788480;          // xkb bf16 [48][112][128] (344,064 slots)
constexpr size_t OFF_XV   = OFF_XK + 344064;            // xv f32 [48][128][112] (688,128)
constexpr size_t OFF_MT   = OFF_XV + 688128;            // MTb bf16 [48][64][128] (393,216 slots)
constexpr size_t OFF_W    = OFF_MT + 393216;            // W f32 [2][3][64][192] (73,728)
constexpr size_t OFF_AT   = OFF_W + 73728;              // ATb bf16 [2][64][64] (4,096 slots)
constexpr size_t OFF_WT   = OFF_AT + 4096;              // t/p/g wT f32 [3][64][64] (12,288)
constexpr size_t OFF_ATTC = OFF_WT + 12288;             // [8][8][3] raw sums
constexpr size_t OFF_MV   = OFF_ATTC + 192;             // [8][8][2]
constexpr size_t OFF_PART = OFF_MV + 128;               // partials [192][256]
// end = 52,685,118 floats ~ 210.7 MiB

#define A0SQ 0.9998000199986667f
#define A1SQ 1.9996000399973335e-4f
#define A2SQ 1.9996000399973334e-8f

typedef __attribute__((ext_vector_type(8))) short bf16x8;
typedef __attribute__((ext_vector_type(4))) float f32x4;

__device__ inline ushort f2bf(float f) {
    uint u = __float_as_uint(f);
    return (ushort)((u + 0x7fffu + ((u >> 16) & 1u)) >> 16);
}

// ---------------- input transpose: f32 [64][128][128] -> bf16 [y][x][64] ----------------
__global__ __launch_bounds__(256) void k_xt(const float* __restrict__ in0, const float* __restrict__ in1,
                                            ushort* __restrict__ xt0, ushort* __restrict__ xt1) {
    __shared__ float L[64 * 130];
    const int y = blockIdx.x, b = blockIdx.y, tid = threadIdx.x;
    const float* in = blockIdx.z ? in1 : in0;
    ushort* xt = blockIdx.z ? xt1 : xt0;
    const float* ib = in + (((size_t)b * 64) << 14) + (y << 7);
    for (int r = 0; r < 32; ++r) {
        int idx = tid + (r << 8); int ch = idx >> 7; int x = idx & 127;
        L[ch * 130 + x] = ib[((size_t)ch << 14) + x];
    }
    __syncthreads();
    const int x = tid >> 1, seg = tid & 1;
    ushort* ob = xt + ((size_t)(b * 128 + y) * 128 + x) * 64 + seg * 32;
    uint pk[16];
#pragma unroll
    for (int c = 0; c < 16; ++c) {
        uint lo = f2bf(L[(seg * 32 + 2 * c) * 130 + x]);
        uint hi = f2bf(L[(seg * 32 + 2 * c + 1) * 130 + x]);
        pk[c] = lo | (hi << 16);
    }
    uint4* o4 = (uint4*)ob;
#pragma unroll
    for (int c = 0; c < 4; ++c) o4[c] = make_uint4(pk[4 * c], pk[4 * c + 1], pk[4 * c + 2], pk[4 * c + 3]);
}

// ---------------- weight re-layout: f32 [oc][ic][3][3] -> bf16 [t][oc][ic] ----------------
__global__ __launch_bounds__(256) void k_wt(const float* __restrict__ w1, const float* __restrict__ w2,
                                            ushort* __restrict__ wt1, ushort* __restrict__ wt2) {
    int id = blockIdx.x * 256 + threadIdx.x;
    if (id >= 147456) return;
    int cs = id / 73728; int rem = id - cs * 73728;
    int t = rem >> 13; int oc = (rem >> 6) & 127; int ic = rem & 63;
    const float* w = cs ? w2 : w1;
    (cs ? wt2 : wt1)[rem] = f2bf(w[((size_t)(oc * 64 + ic)) * 9 + t]);
}

// ---------------- conv 3x3 SAME 64->128 bf16 MFMA; output bf16 [n][128c] ----------------
__global__ __launch_bounds__(256) void k_convm(const ushort* __restrict__ Xt0, const ushort* __restrict__ Xt1,
                                               const ushort* __restrict__ Wt0, const ushort* __restrict__ Wt1,
                                               ushort* __restrict__ out_base) {
    __shared__ ushort smem[2 * 128 * 72];
    ushort* lds_w = smem;
    ushort* lds_x = smem + 128 * 72;
    const int tid = threadIdx.x;
    const int y = blockIdx.x, b = blockIdx.y;
    const ushort* Xt = blockIdx.z ? Xt1 : Xt0;
    const ushort* Wt = blockIdx.z ? Wt1 : Wt0;
    ushort* out = out_base + (size_t)blockIdx.z * 16777216;
    const int l = tid & 63;
    const int wv = __builtin_amdgcn_readfirstlane(tid >> 6);
    const int lr = l & 15;
    const int q = l >> 4;
    const int cr = tid >> 1;
    const int seg = tid & 1;

    f32x4 acc[2][8];
#pragma unroll
    for (int f = 0; f < 2; ++f)
#pragma unroll
        for (int g = 0; g < 8; ++g)
#pragma unroll
            for (int r = 0; r < 4; ++r) acc[f][g][r] = 0.f;

#pragma unroll 1
    for (int t = 0; t < 9; ++t) {
        const int dy = t / 3, dx = t - dy * 3;
        const int srow = y + dy - 1;
        {
            const uint4* s = (const uint4*)(Wt + ((size_t)(t * 128 + cr) * 64 + seg * 32));
            uint4* d = (uint4*)(lds_w + cr * 72 + seg * 32);
            d[0] = s[0]; d[1] = s[1]; d[2] = s[2]; d[3] = s[3];
        }
        {
            const int sx = cr + dx - 1;
            const bool v = (srow >= 0) & (srow < 128) & (sx >= 0) & (sx < 128);
            const uint4* s = (const uint4*)(Xt + (((size_t)(b * 128 + srow) * 128 + sx) * 64 + seg * 32));
            uint4 z = make_uint4(0, 0, 0, 0);
            uint4 r0 = v ? s[0] : z, r1 = v ? s[1] : z, r2 = v ? s[2] : z, r3 = v ? s[3] : z;
            uint4* d = (uint4*)(lds_x + cr * 72 + seg * 32);
            d[0] = r0; d[1] = r1; d[2] = r2; d[3] = r3;
        }
        __syncthreads();
#pragma unroll
        for (int h = 0; h < 2; ++h) {
            const int ko = h * 32 + q * 8;
            bf16x8 a0 = *(const bf16x8*)(lds_w + (wv * 32 + lr) * 72 + ko);
            bf16x8 a1 = *(const bf16x8*)(lds_w + (wv * 32 + 16 + lr) * 72 + ko);
#pragma unroll
            for (int g = 0; g < 8; ++g) {
                bf16x8 bb = *(const bf16x8*)(lds_x + (g * 16 + lr) * 72 + ko);
                acc[0][g] = __builtin_amdgcn_mfma_f32_16x16x32_bf16(a0, bb, acc[0][g], 0, 0, 0);
                acc[1][g] = __builtin_amdgcn_mfma_f32_16x16x32_bf16(a1, bb, acc[1][g], 0, 0, 0);
            }
        }
        __syncthreads();
    }
    uint* T = (uint*)smem;
#pragma unroll
    for (int f = 0; f < 2; ++f)
#pragma unroll
        for (int g = 0; g < 8; ++g) {
            uint lo = (uint)f2bf(acc[f][g][0]) | ((uint)f2bf(acc[f][g][1]) << 16);
            uint hi = (uint)f2bf(acc[f][g][2]) | ((uint)f2bf(acc[f][g][3]) << 16);
            int dw = (g * 16 + lr) * 68 + wv * 16 + f * 8 + q * 2;
            T[dw] = lo; T[dw + 1] = hi;
        }
    __syncthreads();
    const int x = tid >> 1, sg = tid & 1;
    ushort* ob = out + ((size_t)(b * 128 + y) * 128 + x) * 128 + sg * 64;
    const uint* src = &T[x * 68 + sg * 32];
#pragma unroll
    for (int j = 0; j < 8; ++j) {
        uint4 vv = *(const uint4*)(src + 4 * j);
        *(uint4*)(ob + j * 8) = vv;
    }
}

// ---------------- pyramid pooling via 2D prefix sums ----------------
struct PoolPtrs { const float* src[6]; };

__global__ __launch_bounds__(256) void k_pool(PoolPtrs pp, float* __restrict__ ws) {
    extern __shared__ float P[];
    const int plane = blockIdx.x;
    const int tid = threadIdx.x;
    int tI, h; size_t toff; int base;
    if      (plane < 512)  { tI = 0; h = 128; toff = 0;      base = 0;    }
    else if (plane < 1536) { tI = 1; h = 64;  toff = 56320;  base = 512;  }
    else if (plane < 3584) { tI = 2; h = 32;  toff = 168960; base = 1536; }
    else if (plane < 4096) { tI = 3; h = 128; toff = 394240; base = 3584; }
    else if (plane < 5120) { tI = 4; h = 64;  toff = 450560; base = 4096; }
    else                   { tI = 5; h = 32;  toff = 563200; base = 5120; }
    const int local = plane - base;
    const float* img = pp.src[tI] + (size_t)local * h * h;
    const int stride = h + 1;
    const int hh = h * h;
    for (int f = tid; f < hh; f += 256) {
        int r = f / h; int cc = f - r * h;
        P[r * stride + cc] = img[f];
    }
    __syncthreads();
    if (tid < h) {
        float cur = 0.f; const int rb = tid * stride;
        for (int cc = 0; cc < h; ++cc) { cur += P[rb + cc]; P[rb + cc] = cur; }
    }
    __syncthreads();
    if (tid < h) {
        float cur = 0.f;
        for (int r = 0; r < h; ++r) { int a = r * stride + tid; cur += P[a]; P[a] = cur; }
    }
    __syncthreads();
    if (tid < 110) {
        int s, off2;
        if (tid == 0)      { s = 1; off2 = 0; }
        else if (tid < 10) { s = 3; off2 = 1; }
        else if (tid < 46) { s = 6; off2 = 10; }
        else               { s = 8; off2 = 46; }
        int r = tid - off2; int j = r / s; int q = r - j * s;
        const int n = h + 2;
        int ra = (j * n) / s,       rb2 = ((j + 1) * n + s - 1) / s;
        int ca = (q * n) / s,       cb2 = ((q + 1) * n + s - 1) / s;
        float area = (float)((rb2 - ra) * (cb2 - ca));
        int r0 = ra - 1; if (r0 < 0) r0 = 0;  int r1 = rb2 - 1; if (r1 > h) r1 = h;
        int c0 = ca - 1; if (c0 < 0) c0 = 0;  int c1 = cb2 - 1; if (c1 > h) c1 = h;
        float ssum = 0.f;
        if (r1 > r0 && c1 > c0) {
            int ri = r1 - 1, rj = r0 - 1, ci = c1 - 1, cj = c0 - 1;
            float f11 = P[ri * stride + ci];
            float f01 = (rj < 0) ? 0.f : P[rj * stride + ci];
            float f10 = (cj < 0) ? 0.f : P[ri * stride + cj];
            float f00 = (rj < 0 || cj < 0) ? 0.f : P[rj * stride + cj];
            ssum = f11 - f01 - f10 + f00;
        }
        ws[OFF_POOL + toff + (size_t)local * 110 + tid] = ssum / area;
    }
}

// ---------------- small weight precomputes ----------------
__global__ __launch_bounds__(256) void k_pkw(const float* __restrict__ f1, const float* __restrict__ f2,
                                             const float* __restrict__ m1, const float* __restrict__ m2,
                                             const float* __restrict__ tw, const float* __restrict__ pw,
                                             const float* __restrict__ gw, float* __restrict__ ws) {
    int id = blockIdx.x * 256 + threadIdx.x;
    if (id < 73728) {
        int c = id % 192; int t = id / 192; int o = t & 63; int t2 = t >> 6; int i = t2 % 3; int st = t2 / 3;
        const float* fu = st ? f2 : f1; const float* ma = st ? m2 : m1;
        float s = 0.f;
        for (int k = 0; k < 64; ++k) s = fmaf(fu[o * 192 + i * 64 + k], ma[k * 192 + c], s);
        ws[OFF_W + id] = s;
    } else if (id < 81920) {
        int x = id - 73728; int o = x & 63; int c = (x >> 6) & 63; int st = x >> 12;
        const float* fu = st ? f2 : f1; const float* ma = st ? m2 : m1;
        float s = 0.f;
        for (int k = 0; k < 192; ++k) s = fmaf(fu[o * 192 + k], ma[(k & 63) * 192 + c], s);
        ((ushort*)(ws + OFF_AT))[(size_t)st * 4096 + o * 64 + c] = f2bf(s);
    } else if (id < 94208) {
        int x = id - 81920; int o = x & 63; int c = (x >> 6) & 63; int f = x >> 12;
        const float* src = (f == 0) ? tw : ((f == 1) ? pw : gw);
        ws[OFF_WT + (size_t)f * 4096 + c * 64 + o] = src[o * 64 + c];
    }
}

// ---------------- xk (bf16 [p][c]) / xv (f32 [c][p]) from pooled features ----------------
struct KvPtrs { const float* k1[3]; const float* k2[3]; const float* v1[3]; const float* v2[3]; };

__global__ __launch_bounds__(256) void k_xkxv(KvPtrs kp, float* __restrict__ ws) {
    int id = blockIdx.x * 256 + threadIdx.x;
    int isV = 0;
    if (id >= 688128) { isV = 1; id -= 688128; }
    int p = id % 112; int t1 = id / 112; int C = t1 & 127; int t2 = t1 >> 7;
    int b = t2 & 7; int t3 = t2 >> 3; int i = t3 % 3; int st = t3 / 3;
    const int ci = 64 << i;
    size_t poff = (size_t)st * 394240 + (i >= 1 ? 56320 : 0) + (i >= 2 ? 112640 : 0);
    const float* kw = isV ? (st ? kp.v2[i] : kp.v1[i]) : (st ? kp.k2[i] : kp.k1[i]);
    float s = 0.f;
    if (p < 110) {
        const float* pl = ws + OFF_POOL + poff + (size_t)b * ci * 110 + p;
        for (int ic = 0; ic < ci; ++ic) s = fmaf(kw[C * ci + ic], pl[(size_t)ic * 110], s);
    }
    if (isV) ws[OFF_XV + id] = s;
    else     ((ushort*)(ws + OFF_XK))[(size_t)t2 * 14336 + p * 128 + C] = f2bf(s);
}

// ---------------- MTb bf16 [t2][o][p(128, zero-pad)] ----------------
__global__ __launch_bounds__(256) void k_mt(float* __restrict__ ws) {
    int id = blockIdx.x * 256 + threadIdx.x;
    int p = id & 127; int o = (id >> 7) & 63; int t2 = id >> 13;
    int sti = t2 >> 3;
    float s = 0.f;
    if (p < 110) {
        const float* Wrow = ws + OFF_W + ((size_t)sti * 64 + o) * 192 + 64;
        const float* xv = ws + OFF_XV + (size_t)t2 * 128 * 112 + p;
        for (int r = 0; r < 128; ++r) s = fmaf(Wrow[r], xv[(size_t)r * 112], s);
    }
    ((ushort*)(ws + OFF_MT))[id] = f2bf(s);
}

// ---------------- fused MFMA attention (barrier-free: pbuf is wave-private) ----------------
__global__ __launch_bounds__(256, 4) void k_attn2(float* __restrict__ ws,
                                                  const float* __restrict__ g_in,
                                                  const float* __restrict__ c_in) {
    __shared__ uint pbuf[128 * 68];                     // P bf16 [n][128p], pitch 68 dwords; rows 32w..32w+31 owned by wave w
    const int tid = threadIdx.x;
    const int w = __builtin_amdgcn_readfirstlane(tid >> 6);
    const int l = tid & 63;
    const int lr = l & 15;
    const int g4 = l >> 4;
    const int n0 = blockIdx.x << 7;
    const int b = blockIdx.y;
    const int st = blockIdx.z;

    const ushort* xqb = (const ushort*)(ws + OFF_XQ);
    const ushort* xkb = (const ushort*)(ws + OFF_XK);
    const ushort* mtb = (const ushort*)(ws + OFF_MT);
    const ushort* atb = (const ushort*)(ws + OFF_AT);
    const ushort* xt  = (const ushort*)(ws + OFF_XT) + (size_t)st * 8388608;

    // zero p=112..127 pad in this wave's own rows (wave-private; no barrier needed)
    {
        int row = 32 * w + (l >> 1);
        int dcol = 56 + ((l & 1) << 2);
#pragma unroll
        for (int j = 0; j < 4; ++j) pbuf[row * 68 + dcol + j] = 0;
    }

    const ushort* xq_base = xqb + ((size_t)(st * 8 + b) * 16384 + n0) * 128;

    f32x4 pacc[4][2];
#pragma unroll
    for (int m = 0; m < 4; ++m)
#pragma unroll
        for (int nt = 0; nt < 2; ++nt)
#pragma unroll
            for (int r = 0; r < 4; ++r) pacc[m][nt][r] = 0.f;

    // residual-matrix term: A(64x64) @ in(64xN)
#pragma unroll
    for (int kk = 0; kk < 2; ++kk) {
        bf16x8 bi[2];
#pragma unroll
        for (int nt = 0; nt < 2; ++nt)
            bi[nt] = *(const bf16x8*)(xt + ((size_t)b * 16384 + n0 + (2 * w + nt) * 16 + lr) * 64 + kk * 32 + g4 * 8);
#pragma unroll
        for (int m = 0; m < 4; ++m) {
            bf16x8 a = *(const bf16x8*)(atb + (size_t)st * 4096 + (m * 16 + lr) * 64 + kk * 32 + g4 * 8);
#pragma unroll
            for (int nt = 0; nt < 2; ++nt)
                pacc[m][nt] = __builtin_amdgcn_mfma_f32_16x16x32_bf16(a, bi[nt], pacc[m][nt], 0, 0, 0);
        }
    }

#pragma unroll 1
    for (int i = 0; i < 3; ++i) {
        const ushort* xk = xkb + (size_t)((st * 3 + i) * 8 + b) * 14336;
        const ushort* mt_p = mtb + (size_t)((st * 3 + i) * 8 + b) * 8192;
        f32x4 sacc[7][2];
#pragma unroll
        for (int m = 0; m < 7; ++m)
#pragma unroll
            for (int nt = 0; nt < 2; ++nt)
#pragma unroll
                for (int r = 0; r < 4; ++r) sacc[m][nt][r] = 0.f;
        // S = xk^T @ xq  (bq reloaded per kk: keeps VGPR low; L2-hot)
#pragma unroll
        for (int kk = 0; kk < 4; ++kk) {
            bf16x8 bq0 = *(const bf16x8*)(xq_base + (size_t)((2 * w + 0) * 16 + lr) * 128 + kk * 32 + g4 * 8);
            bf16x8 bq1 = *(const bf16x8*)(xq_base + (size_t)((2 * w + 1) * 16 + lr) * 128 + kk * 32 + g4 * 8);
#pragma unroll
            for (int m = 0; m < 7; ++m) {
                bf16x8 a = *(const bf16x8*)(xk + (size_t)(m * 16 + lr) * 128 + kk * 32 + g4 * 8);
                sacc[m][0] = __builtin_amdgcn_mfma_f32_16x16x32_bf16(a, bq0, sacc[m][0], 0, 0, 0);
                sacc[m][1] = __builtin_amdgcn_mfma_f32_16x16x32_bf16(a, bq1, sacc[m][1], 0, 0, 0);
            }
        }
        // in-register softmax over p (per column), mask p>=110, clip +-64
#pragma unroll
        for (int nt = 0; nt < 2; ++nt) {
            float mx = -3.0e38f;
#pragma unroll
            for (int m = 0; m < 7; ++m)
#pragma unroll
                for (int r = 0; r < 4; ++r) {
                    int p = m * 16 + g4 * 4 + r;
                    float s = fminf(fmaxf(sacc[m][nt][r], -64.f), 64.f);
                    if (p >= 110) s = -3.0e38f;
                    sacc[m][nt][r] = s;
                    mx = fmaxf(mx, s);
                }
            mx = fmaxf(mx, __shfl_xor(mx, 16));
            mx = fmaxf(mx, __shfl_xor(mx, 32));
            float sum = 0.f;
#pragma unroll
            for (int m = 0; m < 7; ++m)
#pragma unroll
                for (int r = 0; r < 4; ++r) {
                    float e = __expf(sacc[m][nt][r] - mx);
                    sacc[m][nt][r] = e;
                    sum += e;
                }
            sum += __shfl_xor(sum, 16);
            sum += __shfl_xor(sum, 32);
            float inv = 1.f / sum;
            int nloc = (2 * w + nt) * 16 + lr;
#pragma unroll
            for (int m = 0; m < 7; ++m) {
                uint lo = (uint)f2bf(sacc[m][nt][0] * inv) | ((uint)f2bf(sacc[m][nt][1] * inv) << 16);
                uint hi = (uint)f2bf(sacc[m][nt][2] * inv) | ((uint)f2bf(sacc[m][nt][3] * inv) << 16);
                int dw = nloc * 68 + m * 8 + g4 * 2;
                pbuf[dw] = lo; pbuf[dw + 1] = hi;
            }
        }
        // PV: out += MT^T(64x112) @ P(112xN)   (same-wave LDS ordering via lgkmcnt; no barrier)
#pragma unroll
        for (int kk = 0; kk < 4; ++kk) {
            bf16x8 pb0 = *(const bf16x8*)((const ushort*)pbuf + (size_t)((2 * w + 0) * 16 + lr) * 136 + kk * 32 + g4 * 8);
            bf16x8 pb1 = *(const bf16x8*)((const ushort*)pbuf + (size_t)((2 * w + 1) * 16 + lr) * 136 + kk * 32 + g4 * 8);
#pragma unroll
            for (int m = 0; m < 4; ++m) {
                bf16x8 am = *(const bf16x8*)(mt_p + (size_t)(m * 16 + lr) * 128 + kk * 32 + g4 * 8);
                pacc[m][0] = __builtin_amdgcn_mfma_f32_16x16x32_bf16(am, pb0, pacc[m][0], 0, 0, 0);
                pacc[m][1] = __builtin_amdgcn_mfma_f32_16x16x32_bf16(am, pb1, pacc[m][1], 0, 0, 0);
            }
        }
    }
    // epilogue: xf = tanh(acc) + in  (fast tanh via exp)
    const float* gin = (st ? c_in : g_in) + ((size_t)b * 64 << 14);
    float* xf = ws + OFF_XF + (size_t)st * SZ_XF_ST + ((size_t)b * 64 << 14);
#pragma unroll
    for (int m = 0; m < 4; ++m)
#pragma unroll
        for (int nt = 0; nt < 2; ++nt)
#pragma unroll
            for (int r = 0; r < 4; ++r) {
                int o = m * 16 + g4 * 4 + r;
                int n = n0 + (2 * w + nt) * 16 + lr;
                size_t idx = ((size_t)o << 14) + n;
                float v = pacc[m][nt][r];
                float xx = fminf(fmaxf(v, -15.f), 15.f);
                float e = __expf(2.f * xx);
                float th = __fdividef(e - 1.f, e + 1.f);
                xf[idx] = th + gin[idx];
            }
}

// ---------------- t field + fused p,g reductions ----------------
// block: (n0, b). Computes t (store), p,g in registers; per-(b,group) partial sums to OFF_PART.
__global__ __launch_bounds__(256) void k_tpg(float* __restrict__ ws) {
    __shared__ float XG[64 * 65];
    __shared__ float XC[64 * 65];
    const int tid = threadIdx.x;
    const int nb = blockIdx.x; const int n0 = nb << 6; const int b = blockIdx.y;
    const float* srcg = ws + OFF_XF + (size_t)b * 64 * NN;
    const float* srcc = srcg + SZ_XF_ST;
    for (int ff = tid; ff < 4096; ff += 256) {
        int c = ff >> 6; int nn2 = ff & 63;
        XG[c * 65 + nn2] = srcg[((size_t)c << 14) + n0 + nn2];
        XC[c * 65 + nn2] = srcc[((size_t)c << 14) + n0 + nn2];
    }
    __syncthreads();
    const int col = tid & 63; const int qg = __builtin_amdgcn_readfirstlane(tid >> 6);
    const float* WTt = ws + OFF_WT + qg * 16;
    const float* WTp = WTt + 4096;
    const float* WTg = WTt + 8192;
    float t[16], p[16], g[16];
#pragma unroll
    for (int j = 0; j < 16; ++j) { t[j] = 0.f; p[j] = 0.f; g[j] = 0.f; }
#pragma unroll 1
    for (int c = 0; c < 64; ++c) {
        float xg = XG[c * 65 + col];
        float xc = XC[c * 65 + col];
        const float* wt = WTt + (size_t)c * 64;
        const float* wp = WTp + (size_t)c * 64;
        const float* wg = WTg + (size_t)c * 64;
#pragma unroll
        for (int j = 0; j < 16; ++j) {
            t[j] = fmaf(wt[j], xg, t[j]);
            p[j] = fmaf(wp[j], xc, p[j]);
            g[j] = fmaf(wg[j], xc, g[j]);
        }
    }
    // store t field
    float* dst = ws + OFF_XQ + (size_t)b * 64 * NN + n0 + col;
#pragma unroll
    for (int j = 0; j < 16; ++j) dst[(size_t)(qg * 16 + j) << 14] = t[j];
    // partial sums s0=sum g, s1=sum p*g, s2=sum p^2*g  per group (wave qg covers groups 2qg,2qg+1)
    float s[2][3];
#pragma unroll
    for (int gi = 0; gi < 2; ++gi) { s[gi][0] = 0.f; s[gi][1] = 0.f; s[gi][2] = 0.f; }
#pragma unroll
    for (int j = 0; j < 16; ++j) {
        int gi = j >> 3;
        s[gi][0] += g[j];
        s[gi][1] = fmaf(p[j], g[j], s[gi][1]);
        s[gi][2] = fmaf(p[j] * p[j], g[j], s[gi][2]);
    }
#pragma unroll
    for (int off = 1; off < 64; off <<= 1) {
#pragma unroll
        for (int gi = 0; gi < 2; ++gi)
#pragma unroll
            for (int k = 0; k < 3; ++k) s[gi][k] += __shfl_xor(s[gi][k], off);
    }
    if ((tid & 63) == 0) {
#pragma unroll
        for (int gi = 0; gi < 2; ++gi)
#pragma unroll
            for (int k = 0; k < 3; ++k)
                ws[OFF_PART + ((size_t)((b * 8 + (2 * qg + gi)) * 3 + k) << 8) + nb] = s[gi][k];
    }
}

// ---------------- deterministic partial reduction -> attc raw sums ----------------
__global__ __launch_bounds__(64) void k_attc(float* __restrict__ ws) {
    const int id = blockIdx.x;                          // 0..191
    const int l = threadIdx.x;
    const float4 v = *(const float4*)(ws + OFF_PART + ((size_t)id << 8) + l * 4);
    float s = v.x + v.y + v.z + v.w;
#pragma unroll
    for (int off = 1; off < 64; off <<= 1) s += __shfl_xor(s, off);
    if (l == 0) ws[OFF_ATTC + id] = s;
}

// ---------------- GroupNorm stats ----------------
__global__ __launch_bounds__(256) void k_stats(float* __restrict__ ws, const float* __restrict__ zw) {
    __shared__ float r0[256], r1[256];
    const int g = blockIdx.x, b = blockIdx.y, tid = threadIdx.x;
    const float* tf = ws + OFF_XQ + ((size_t)(b * 64 + g * 8) << 14);
    const float* a = ws + OFF_ATTC + (size_t)(b * 8 + g) * 3;
    const float c0 = A0SQ * a[0], c1 = A1SQ * a[1], c2 = A2SQ * a[2];
    const float* z = zw + (size_t)g * 64;
    float sum = 0.f, ssq = 0.f;
    for (int n = tid; n < 16384; n += 256) {
        float y[8];
#pragma unroll
        for (int pl = 0; pl < 8; ++pl) { float tv = tf[((size_t)pl << 14) + n]; y[pl] = fmaf(fmaf(c2, tv, c1), tv, c0); }
#pragma unroll
        for (int o = 0; o < 8; ++o) {
            float xz = 0.f;
#pragma unroll
            for (int i2 = 0; i2 < 8; ++i2) xz = fmaf(z[o * 8 + i2], y[i2], xz);
            sum += xz; ssq = fmaf(xz, xz, ssq);
        }
    }
    r0[tid] = sum; r1[tid] = ssq;
    __syncthreads();
    for (int w = 128; w > 0; w >>= 1) {
        if (tid < w) { r0[tid] += r0[tid + w]; r1[tid] += r1[tid + w]; }
        __syncthreads();
    }
    if (tid == 0) {
        float mean = r0[0] * (1.f / 131072.f);
        float var = r1[0] * (1.f / 131072.f) - mean * mean;
        float* mv = ws + OFF_MV + (size_t)(b * 8 + g) * 2;
        mv[0] = mean; mv[1] = rsqrtf(var + 1e-5f);
    }
}

// ---------------- final ----------------
__global__ __launch_bounds__(256) void k_final(float* __restrict__ ws, const float* __restrict__ zw,
                                               const float* __restrict__ gnw, const float* __restrict__ gnb,
                                               const float* __restrict__ g_in, float* __restrict__ out) {
    int id = blockIdx.x * 256 + threadIdx.x;
    int n = id & 16383; int g = (id >> 14) & 7; int b = id >> 17;
    const float* a = ws + OFF_ATTC + (size_t)(b * 8 + g) * 3;
    const float c0 = A0SQ * a[0], c1 = A1SQ * a[1], c2 = A2SQ * a[2];
    const float* mv = ws + OFF_MV + (size_t)(b * 8 + g) * 2;
    const float mean = mv[0], istd = mv[1];
    const float* z = zw + (size_t)g * 64;
    const float* tf = ws + OFF_XQ + ((size_t)(b * 64 + g * 8) << 14) + n;
    float y[8];
#pragma unroll
    for (int pl = 0; pl < 8; ++pl) { float tv = tf[(size_t)pl << 14]; y[pl] = fmaf(fmaf(c2, tv, c1), tv, c0); }
    const size_t cb = ((size_t)(b * 64 + g * 8) << 14) + n;
    const float* xg = ws + OFF_XF + cb;
    const float* gi = g_in + cb;
    float* op = out + cb;
#pragma unroll
    for (int o = 0; o < 8; ++o) {
        float xz = 0.f;
#pragma unroll
        for (int i2 = 0; i2 < 8; ++i2) xz = fmaf(z[o * 8 + i2], y[i2], xz);
        int ch = g * 8 + o;
        float v = fmaf((xz - mean) * istd, gnw[ch], gnb[ch]) + xg[(size_t)o << 14] + gi[(size_t)o << 14];
        op[(size_t)o << 14] = v;
    }
}

// ---------------- host launch ----------------
extern "C" void kernel_launch(void* const* d_in, const int* in_sizes, int n_in,
                              void* d_out, int out_size, void* d_ws, size_t ws_size,
                              hipStream_t stream) {
    const float* in_g = (const float*)d_in[0];
    const float* in_c = (const float*)d_in[1];
    float* ws = (float*)d_ws;
    float* out = (float*)d_out;

    ushort* xqb  = (ushort*)(ws + OFF_XQ);
    ushort* xt_g = (ushort*)(ws + OFF_XT);
    ushort* xt_c = xt_g + 8388608;
    ushort* wt_g = (ushort*)(ws + OFF_XF);
    ushort* wt_c = wt_g + 73728;

    // input transpose + weight re-layout (bf16)
    k_xt<<<dim3(128, 8, 2), 256, 0, stream>>>(in_g, in_c, xt_g, xt_c);
    k_wt<<<576, 256, 0, stream>>>((const float*)d_in[20], (const float*)d_in[21], wt_g, wt_c);

    // MFMA convs -> xqb bf16 [n][c] slabs (both streams in one grid)
    k_convm<<<dim3(128, 8, 2), 256, 0, stream>>>(xt_g, xt_c, wt_g, wt_c, xqb);

    // pyramid pooling of raw features
    PoolPtrs pp;
    pp.src[0] = (const float*)d_in[3];  pp.src[1] = (const float*)d_in[9];  pp.src[2] = (const float*)d_in[15];
    pp.src[3] = (const float*)d_in[2];  pp.src[4] = (const float*)d_in[8];  pp.src[5] = (const float*)d_in[14];
    k_pool<<<7168, 256, 128 * 129 * 4, stream>>>(pp, ws);

    // weight precomputes
    k_pkw<<<368, 256, 0, stream>>>((const float*)d_in[24], (const float*)d_in[25],
                                   (const float*)d_in[22], (const float*)d_in[23],
                                   (const float*)d_in[26], (const float*)d_in[27],
                                   (const float*)d_in[28], ws);

    // xk (bf16), xv (f32)
    KvPtrs kp;
    kp.k1[0] = (const float*)d_in[4];  kp.k1[1] = (const float*)d_in[10]; kp.k1[2] = (const float*)d_in[16];
    kp.k2[0] = (const float*)d_in[6];  kp.k2[1] = (const float*)d_in[12]; kp.k2[2] = (const float*)d_in[18];
    kp.v1[0] = (const float*)d_in[5];  kp.v1[1] = (const float*)d_in[11]; kp.v1[2] = (const float*)d_in[17];
    kp.v2[0] = (const float*)d_in[7];  kp.v2[1] = (const float*)d_in[13]; kp.v2[2] = (const float*)d_in[19];
    k_xkxv<<<5376, 256, 0, stream>>>(kp, ws);

    // MTb bf16
    k_mt<<<3072, 256, 0, stream>>>(ws);

    // fused MFMA attention -> x_gray / x_color
    k_attn2<<<dim3(128, 8, 2), 256, 0, stream>>>(ws, in_g, in_c);

    // t field + fused p,g reductions
    k_tpg<<<dim3(256, 8), 256, 0, stream>>>(ws);
    k_attc<<<192, 64, 0, stream>>>(ws);

    // GN stats, final
    k_stats<<<dim3(8, 8), 256, 0, stream>>>(ws, (const float*)d_in[29]);
    k_final<<<4096, 256, 0, stream>>>(ws, (const float*)d_in[29], (const float*)d_in[30],
                                      (const float*)d_in[31], in_g, out);
}